// Round 9
// baseline (99.724 us; speedup 1.0000x reference)
//
#include <hip/hip_runtime.h>

#define BATCH 1024
#define ITERS 20
#define SIGMA_C 0.1f
#define REG_C 1e-8f

typedef float f2 __attribute__((ext_vector_type(2)));

__device__ __forceinline__ float frcp(float x) { return __builtin_amdgcn_rcpf(x); }
__device__ __forceinline__ float readlane_f(float v, int l) {
    return __int_as_float(__builtin_amdgcn_readlane(__float_as_int(v), l));
}
__device__ __forceinline__ f2 mkf2(float a, float b) { f2 r; r.x = a; r.y = b; return r; }
// a*b+c on packed f32; fp-contract fuses to v_pk_fma_f32 (full-rate 2xFP32 on CDNA)
__device__ __forceinline__ f2 fma2(f2 a, f2 b, f2 c) { return a * b + c; }

// Single-wave workgroup: LDS ops from one wave are processed in order by the
// LDS pipe, so write->read RAW needs no s_barrier / full lgkmcnt(0) drain —
// only a compiler fence so the scheduler keeps program order and doesn't
// cache LDS values in registers across the point. Zero instructions emitted.
#define WFENCE() do { __builtin_amdgcn_wave_barrier(); asm volatile("" ::: "memory"); } while (0)

// DPP helper: ctrl must be a literal
#define DPPF(v, ctrl) \
    __int_as_float(__builtin_amdgcn_update_dpp(0, __float_as_int(v), ctrl, 0xf, 0xf, true))

__device__ __forceinline__ float wave_sum(float v) {
    v += DPPF(v, 0xB1);   // quad_perm 1,0,3,2
    v += DPPF(v, 0x4E);   // quad_perm 2,3,0,1
    v += DPPF(v, 0x141);  // row_half_mirror
    v += DPPF(v, 0x140);  // row_mirror
    v += __shfl_xor(v, 16);
    v += __shfl_xor(v, 32);
    return v;
}

// fused 3-stream reduction step: 2 sums (p1,p2) + 1 max (q)
#define RED3_DPP(ctrl) do { \
    p1 += DPPF(p1, ctrl); \
    p2 += DPPF(p2, ctrl); \
    q = fmaxf(q, DPPF(q, ctrl)); \
} while (0)

// One wave (64 lanes) per batch item. Lane k<40 owns constraint rows
// {B:20+k, C:60+k, D:100+k, E:140+k} and e-vars w2a=w[10+k], w2b=w[50+k].
// Lanes<20 own the u-box rows. w1[10] replicated in all lanes.
// S-formation: lanes 10-59 each own 2 adjacent S entries (register-cached
// outer-product rows as packed f2); lanes 0-9 own rhs row `lane`, kept
// IN-REGISTER (same lanes run the solve -> no LDS round-trip for rhs).
// Solve: LU w/ readlane broadcasts, rows on lanes 0-9.
__global__ __launch_bounds__(64, 1) void ipm_kernel(
    const float* __restrict__ x, const float* __restrict__ u0p,
    const float* __restrict__ Qs, const float* __restrict__ Rs,
    const float* __restrict__ Ad, const float* __restrict__ Bd,
    float* __restrict__ out)
{
    const int item = blockIdx.x;
    const int lane = threadIdx.x;

    __shared__ __align__(16) float BLc[10 * 40];  // B column-major: BLc[j][k]=B[k][j]
    __shared__ __align__(16) float QBc[10 * 40];  // (Q_diag B) column-major
    __shared__ __align__(16) float yL4[40];
    __shared__ __align__(16) float QhL[10 * 12];
    __shared__ __align__(16) float SL[10 * 12];   // cols 0-9 = S (col 10-11 pad)
    __shared__ __align__(16) float cg[80];        // [0,40)=coeff, [40,80)=gvc
    __shared__ float duL[20], ltL[20];
    __shared__ float axL[40];
    __shared__ float pvL[10], wL[10];
    __shared__ float QL[16];
    __shared__ float TL[40];    // T[i][r] = (A^i B)[r]
    __shared__ float AhL[160];  // A_hat [40][4]

    // ---------------- prologue ----------------
    const int r2 = (lane >> 2) & 3, c2 = lane & 3;
    const int r4 = lane & 3;

    if (lane < 16) {
        float acc = 0.f;
        #pragma unroll
        for (int k = 0; k < 4; ++k) acc += Qs[r2 * 4 + k] * Qs[c2 * 4 + k];
        QL[lane] = acc;
    }

    // A powers -> A_hat (shfl chain)
    float acol[4];
    #pragma unroll
    for (int k = 0; k < 4; ++k) acol[k] = Ad[k * 4 + c2];
    float cur = Ad[r2 * 4 + c2];
    if (lane < 16) AhL[r2 * 4 + c2] = cur;
    #pragma unroll
    for (int i = 1; i < 10; ++i) {
        float nx = 0.f;
        #pragma unroll
        for (int k = 0; k < 4; ++k) nx += __shfl(cur, r2 * 4 + k) * acol[k];
        cur = nx;
        if (lane < 16) AhL[(4 * i + r2) * 4 + c2] = cur;
    }

    // T chain
    float arow[4];
    #pragma unroll
    for (int k = 0; k < 4; ++k) arow[k] = Ad[r4 * 4 + k];
    float tc = Bd[r4];
    if (lane < 4) TL[r4] = tc;
    #pragma unroll
    for (int i = 1; i < 10; ++i) {
        float nt = 0.f;
        #pragma unroll
        for (int k = 0; k < 4; ++k) nt += arow[k] * __shfl(tc, k);
        tc = nt;
        if (lane < 4) TL[i * 4 + r4] = nt;
    }
    __syncthreads();

    // per-lane B_hat row
    const int kk40 = (lane < 40) ? lane : 39;
    const int ib = lane >> 2;
    float b[10];
    #pragma unroll
    for (int j = 0; j < 10; ++j) {
        int dd = ib - j;
        int dc = dd < 0 ? 0 : (dd > 9 ? 9 : dd);
        float v = TL[dc * 4 + r4];
        b[j] = (dd >= 0 && lane < 40) ? v : 0.f;
    }

    const float xv0 = x[item * 4 + 0], xv1 = x[item * 4 + 1];
    const float xv2 = x[item * 4 + 2], xv3 = x[item * 4 + 3];
    const float ax = AhL[kk40 * 4 + 0] * xv0 + AhL[kk40 * 4 + 1] * xv1 +
                     AhL[kk40 * 4 + 2] * xv2 + AhL[kk40 * 4 + 3] * xv3;
    if (lane < 40) axL[lane] = ax;

    const int gbase = lane & ~3;
    float yv = 0.f;
    #pragma unroll
    for (int rp_ = 0; rp_ < 4; ++rp_) yv += QL[r4 * 4 + rp_] * __shfl(ax, gbase + rp_);
    if (lane < 40) yL4[lane] = yv;
    #pragma unroll
    for (int cc = 0; cc < 10; ++cc) {
        float acc = 0.f;
        #pragma unroll
        for (int rp_ = 0; rp_ < 4; ++rp_) acc += QL[r4 * 4 + rp_] * __shfl(b[cc], gbase + rp_);
        if (lane < 40) QBc[cc * 40 + lane] = acc;
    }
    if (lane < 40) {
        #pragma unroll
        for (int j = 0; j < 10; ++j) BLc[j * 40 + lane] = b[j];
    }
    __syncthreads();

    // pv (lanes 0-9)
    if (lane < 10) {
        const float4* br = reinterpret_cast<const float4*>(&BLc[lane * 40]);
        const float4* yy = reinterpret_cast<const float4*>(yL4);
        float acc = 0.f;
        #pragma unroll
        for (int i = 0; i < 10; ++i) {
            const float4 a_ = br[i], b_ = yy[i];
            acc += a_.x * b_.x + a_.y * b_.y + a_.z * b_.z + a_.w * b_.w;
        }
        pvL[lane] = 2.f * acc;
    }
    // Qh (100 tasks)
    const float R2v = Rs[0] * Rs[0];
    #pragma unroll
    for (int p = 0; p < 2; ++p) {
        const int t = lane + 64 * p;
        if (t < 100) {
            const int aa = t / 10, bb = t - aa * 10;
            const float4* ba = reinterpret_cast<const float4*>(&BLc[aa * 40]);
            const float4* qb = reinterpret_cast<const float4*>(&QBc[bb * 40]);
            float acc = (aa == bb) ? R2v : 0.f;
            #pragma unroll
            for (int i = 0; i < 10; ++i) {
                const float4 a_ = ba[i], b_ = qb[i];
                acc += a_.x * b_.x + a_.y * b_.y + a_.z * b_.z + a_.w * b_.w;
            }
            QhL[aa * 12 + bb] = acc;
        }
    }
    __syncthreads();

    // ---------------- per-lane register task caches (packed f2) ----------------
    const bool rLane = (lane < 10);                  // rhs producers == solve rows
    const bool sLane = (lane >= 10 && lane < 60);    // S-entry pairs
    const int t1 = sLane ? 2 * (lane - 10) : 0;
    const int srow = t1 / 10, sc1 = t1 - srow * 10, sc2 = sc1 + 1;
    f2 tA[20], tB[20];
    float qh_a = 0.f, qh_b = 0.f;
    bool diagA = false, diagB = false;
    if (sLane) {
        const float4* br = reinterpret_cast<const float4*>(&BLc[srow * 40]);
        const float4* b1 = reinterpret_cast<const float4*>(&BLc[sc1 * 40]);
        const float4* b2 = reinterpret_cast<const float4*>(&BLc[sc2 * 40]);
        #pragma unroll
        for (int i = 0; i < 10; ++i) {
            const float4 r_ = br[i], u_ = b1[i], v_ = b2[i];
            tA[2*i]   = mkf2(r_.x * u_.x, r_.y * u_.y);
            tA[2*i+1] = mkf2(r_.z * u_.z, r_.w * u_.w);
            tB[2*i]   = mkf2(r_.x * v_.x, r_.y * v_.y);
            tB[2*i+1] = mkf2(r_.z * v_.z, r_.w * v_.w);
        }
        qh_a = 2.f * QhL[srow * 12 + sc1];
        qh_b = 2.f * QhL[srow * 12 + sc2];
        diagA = (srow == sc1); diagB = (srow == sc2);
    } else if (rLane) {
        const float4* br = reinterpret_cast<const float4*>(&BLc[lane * 40]);
        #pragma unroll
        for (int i = 0; i < 10; ++i) {
            const float4 r_ = br[i];
            tA[2*i]   = mkf2(r_.x, r_.y);
            tA[2*i+1] = mkf2(r_.z, r_.w);
        }
        #pragma unroll
        for (int c = 0; c < 5; ++c)
            tB[c] = mkf2(QhL[lane * 12 + 2*c], QhL[lane * 12 + 2*c + 1]);
        qh_a = pvL[lane];
    }
    __syncthreads();

    // ---------------- state init ----------------
    float s_B = fmaxf(4.f - ax, 1.f), s_C = fmaxf(4.f + ax, 1.f);
    float s_D = 1.f, s_E = 1.f, s_U = 1.f;
    float l_B = 1.f, l_C = 1.f, l_D = 1.f, l_E = 1.f, l_U = 1.f;
    float w2a = 0.f, w2b = 0.f;
    float w1[10];
    #pragma unroll
    for (int r = 0; r < 10; ++r) w1[r] = 0.f;
    float w1own = 0.f, nu = 0.f;
    const float uu0 = u0p[item];
    const bool a40 = lane < 40, a20 = lane < 20;
    const int jown = (lane < 10) ? lane : lane - 10;
    const float sgnU = (lane < 10) ? 1.f : -1.f;

    // initial mu = SIGMA * sum(s*l)/180 (one-time; thereafter via alpha-polynomial)
    float mu;
    {
        float part = a40 ? (s_B * l_B + s_C * l_C + s_D * l_D + s_E * l_E) : 0.f;
        if (a20) part += s_U * l_U;
        mu = SIGMA_C * wave_sum(part) * (1.f / 180.f);
    }

    // ---------------- IPM iterations ----------------
    for (int it = 0; it < ITERS; ++it) {
        const float rs_B = frcp(s_B), rs_C = frcp(s_C), rs_D = frcp(s_D),
                    rs_E = frcp(s_E), rs_U = frcp(s_U);
        const float rl_B = frcp(l_B), rl_C = frcp(l_C), rl_D = frcp(l_D),
                    rl_E = frcp(l_E), rl_U = frcp(l_U);
        const float d_B = l_B * rs_B, d_C = l_C * rs_C, d_D = l_D * rs_D,
                    d_E = l_E * rs_E, d_U = l_U * rs_U;

        f2 bu = mkf2(0.f, 0.f);
        #pragma unroll
        for (int j = 0; j < 5; ++j)
            bu = fma2(mkf2(b[2*j], b[2*j+1]), mkf2(w1[2*j], w1[2*j+1]), bu);
        const float Bu = bu.x + bu.y;

        const float rp_B = Bu - w2a + s_B - (4.f - ax);
        const float rp_C = -Bu - w2b + s_C - (4.f + ax);
        const float rp_D = -w2a + s_D;
        const float rp_E = -w2b + s_E;
        const float rp_U = sgnU * w1own + s_U - 0.5f;

        const float tm_B = (mu - l_B * s_B + l_B * rp_B) * rs_B;
        const float tm_C = (mu - l_C * s_C + l_C * rp_C) * rs_C;
        const float tm_D = (mu - l_D * s_D + l_D * rp_D) * rs_D;
        const float tm_E = (mu - l_E * s_E + l_E * rp_E) * rs_E;
        const float tm_U = (mu - l_U * s_U + l_U * rp_U) * rs_U;
        const float lt_B = l_B + tm_B, lt_C = l_C + tm_C, lt_D = l_D + tm_D,
                    lt_E = l_E + tm_E;

        const float D22a = 2.f + d_B + d_D + REG_C, D22b = 2.f + d_C + d_E + REG_C;
        const float rda = frcp(D22a), rdb = frcp(D22b);
        const float rw2a = -2.f * w2a + lt_B + lt_D;
        const float rw2b = -2.f * w2b + lt_C + lt_E;
        const float coeff = (d_B + d_C) - d_B * d_B * rda - d_C * d_C * rdb;
        const float gvc = (d_B * rw2a * rda - d_C * rw2b * rdb) - (lt_B - lt_C);

        if (a40) { cg[lane] = coeff; cg[40 + lane] = gvc; }
        if (a20) { duL[lane] = d_U; ltL[lane] = l_U + tm_U; }
        WFENCE();   // single wave: in-order DS pipe makes RAW safe without barrier

        // ---- cf loads issued immediately (pipeline behind the writes) ----
        float4 cf4[10];
        {
            const float4* cp = reinterpret_cast<const float4*>(cg + (rLane ? 40 : 0));
            #pragma unroll
            for (int i = 0; i < 10; ++i) cf4[i] = cp[i];
        }

        // ---- p0 = sum(s*l) reduction in the load shadow ----
        float p0 = a40 ? (s_B * l_B + s_C * l_C + s_D * l_D + s_E * l_E) : 0.f;
        if (a20) p0 += s_U * l_U;
        p0 = wave_sum(p0);

        // ---- S + rhs formation (packed-f2 register tables) ----
        float rhs_loc = 0.f;
        if (sLane) {
            f2 aA0 = mkf2(0.f, 0.f), aA1 = mkf2(0.f, 0.f);
            f2 aB0 = mkf2(0.f, 0.f), aB1 = mkf2(0.f, 0.f);
            #pragma unroll
            for (int i = 0; i < 10; ++i) {
                const f2 cl = mkf2(cf4[i].x, cf4[i].y);
                const f2 ch = mkf2(cf4[i].z, cf4[i].w);
                aA0 = fma2(tA[2*i], cl, aA0); aA1 = fma2(tA[2*i+1], ch, aA1);
                aB0 = fma2(tB[2*i], cl, aB0); aB1 = fma2(tB[2*i+1], ch, aB1);
            }
            float vA = ((aA0.x + aA0.y) + (aA1.x + aA1.y)) + qh_a;
            float vB = ((aB0.x + aB0.y) + (aB1.x + aB1.y)) + qh_b;
            if (diagA || diagB) {
                const float dd = duL[srow] + duL[10 + srow] + REG_C;
                if (diagA) vA += dd; else vB += dd;
            }
            *reinterpret_cast<float2*>(&SL[srow * 12 + sc1]) = make_float2(vA, vB);
        } else if (rLane) {
            f2 a0 = mkf2(0.f, 0.f), a1 = mkf2(0.f, 0.f);
            #pragma unroll
            for (int i = 0; i < 10; ++i) {
                const f2 cl = mkf2(cf4[i].x, cf4[i].y);
                const f2 ch = mkf2(cf4[i].z, cf4[i].w);
                a0 = fma2(tA[2*i], cl, a0); a1 = fma2(tA[2*i+1], ch, a1);
            }
            const float acc = (a0.x + a0.y) + (a1.x + a1.y);
            f2 qa = mkf2(0.f, 0.f);
            #pragma unroll
            for (int c = 0; c < 5; ++c)
                qa = fma2(tB[c], mkf2(w1[2*c], w1[2*c+1]), qa);
            const float qw = qa.x + qa.y;
            rhs_loc = acc - (2.f * qw + qh_a + ltL[lane] - ltL[10 + lane] +
                             ((lane == 0) ? nu : 0.f));
        }
        WFENCE();   // SL stores (lanes 10-59) ordered before SL reads (lanes 0-9)

        // ---- LU solve: rows on lanes 0-9; rhs is LOCAL (no LDS trip) ----
        float row[11], rBv;
        if (rLane) {
            const float4* s4 = reinterpret_cast<const float4*>(&SL[lane * 12]);
            const float4 q0 = s4[0], q1 = s4[1], q2 = s4[2];
            row[0] = q0.x; row[1] = q0.y; row[2] = q0.z; row[3] = q0.w;
            row[4] = q1.x; row[5] = q1.y; row[6] = q1.z; row[7] = q1.w;
            row[8] = q2.x; row[9] = q2.y;
            (void)q2;
        } else {
            #pragma unroll
            for (int c = 0; c < 10; ++c) row[c] = 0.f;
        }
        row[10] = rhs_loc;
        rBv = (lane == 0) ? 1.f : 0.f;

        #pragma unroll
        for (int kc = 0; kc < 9; ++kc) {
            float pk[11];
            #pragma unroll
            for (int c = kc; c < 11; ++c) pk[c] = readlane_f(row[c], kc);
            const float pB = readlane_f(rBv, kc);
            const float rpiv = frcp(pk[kc]);
            const float f = (lane > kc) ? row[kc] * rpiv : 0.f;
            #pragma unroll
            for (int c = kc + 1; c < 11; ++c) row[c] -= f * pk[c];
            rBv -= f * pB;
        }

        // hoisted diag reciprocals (row coeffs final now)
        float rd[10];
        #pragma unroll
        for (int r = 0; r < 10; ++r) rd[r] = frcp(row[r]);

        float dwAv[10], dwBv[10], ownA = 0.f, ownB = 0.f;
        #pragma unroll
        for (int r = 9; r >= 0; --r) {
            const float bA = readlane_f(row[10] * rd[r], r);
            const float bB = readlane_f(rBv * rd[r], r);
            dwAv[r] = bA; dwBv[r] = bB;
            if (jown == r) { ownA = bA; ownB = bB; }
            const float m_ = (lane < r) ? 1.f : 0.f;
            row[10] -= m_ * row[r] * bA;
            rBv     -= m_ * row[r] * bB;
        }

        const float rn = -(w1[0] - uu0);
        const float nu_d = (dwAv[0] - rn) * frcp(dwBv[0] + REG_C);
        float dw1[10];
        #pragma unroll
        for (int r = 0; r < 10; ++r) dw1[r] = dwAv[r] - nu_d * dwBv[r];
        const float dOwn = ownA - nu_d * ownB;

        f2 bd = mkf2(0.f, 0.f);
        #pragma unroll
        for (int j = 0; j < 5; ++j)
            bd = fma2(mkf2(b[2*j], b[2*j+1]), mkf2(dw1[2*j], dw1[2*j+1]), bd);
        const float Bdw = bd.x + bd.y;

        const float dw2a = (rw2a + d_B * Bdw) * rda;
        const float dw2b = (rw2b - d_C * Bdw) * rdb;

        const float ds_B = -(Bdw - dw2a) - rp_B;
        const float ds_C = (Bdw + dw2b) - rp_C;
        const float ds_D = dw2a - rp_D;
        const float ds_E = dw2b - rp_E;
        const float ds_U = -sgnU * dOwn - rp_U;
        const float dl_B = (mu - l_B * s_B - l_B * ds_B) * rs_B;
        const float dl_C = (mu - l_C * s_C - l_C * ds_C) * rs_C;
        const float dl_D = (mu - l_D * s_D - l_D * ds_D) * rs_D;
        const float dl_E = (mu - l_E * s_E - l_E * ds_E) * rs_E;
        const float dl_U = (mu - l_U * s_U - l_U * ds_U) * rs_U;

        // ---- step ratios via q = max((-dv)*(1/v)), reusing rs_*/rl_* ----
        float q = 0.f, p1 = 0.f, p2 = 0.f;
        if (a40) {
            q = fmaxf(q, (ds_B < -1e-12f) ? -ds_B * rs_B : 0.f);
            q = fmaxf(q, (ds_C < -1e-12f) ? -ds_C * rs_C : 0.f);
            q = fmaxf(q, (ds_D < -1e-12f) ? -ds_D * rs_D : 0.f);
            q = fmaxf(q, (ds_E < -1e-12f) ? -ds_E * rs_E : 0.f);
            q = fmaxf(q, (dl_B < -1e-12f) ? -dl_B * rl_B : 0.f);
            q = fmaxf(q, (dl_C < -1e-12f) ? -dl_C * rl_C : 0.f);
            q = fmaxf(q, (dl_D < -1e-12f) ? -dl_D * rl_D : 0.f);
            q = fmaxf(q, (dl_E < -1e-12f) ? -dl_E * rl_E : 0.f);
            p1 = (s_B * dl_B + l_B * ds_B) + (s_C * dl_C + l_C * ds_C) +
                 (s_D * dl_D + l_D * ds_D) + (s_E * dl_E + l_E * ds_E);
            p2 = ds_B * dl_B + ds_C * dl_C + ds_D * dl_D + ds_E * dl_E;
        }
        if (a20) {
            q = fmaxf(q, (ds_U < -1e-12f) ? -ds_U * rs_U : 0.f);
            q = fmaxf(q, (dl_U < -1e-12f) ? -dl_U * rl_U : 0.f);
            p1 += s_U * dl_U + l_U * ds_U;
            p2 += ds_U * dl_U;
        }
        RED3_DPP(0xB1);
        RED3_DPP(0x4E);
        RED3_DPP(0x141);
        RED3_DPP(0x140);
        p1 += __shfl_xor(p1, 16); p2 += __shfl_xor(p2, 16);
        q = fmaxf(q, __shfl_xor(q, 16));
        p1 += __shfl_xor(p1, 32); p2 += __shfl_xor(p2, 32);
        q = fmaxf(q, __shfl_xor(q, 32));

        const float alpha = 0.99f * ((q > 1.f) ? frcp(q) : 1.f);
        mu = SIGMA_C * (p0 + alpha * (p1 + alpha * p2)) * (1.f / 180.f);

        s_B += alpha * ds_B; s_C += alpha * ds_C; s_D += alpha * ds_D;
        s_E += alpha * ds_E; s_U += alpha * ds_U;
        l_B += alpha * dl_B; l_C += alpha * dl_C; l_D += alpha * dl_D;
        l_E += alpha * dl_E; l_U += alpha * dl_U;
        w2a += alpha * dw2a; w2b += alpha * dw2b;
        #pragma unroll
        for (int r = 0; r < 10; ++r) w1[r] += alpha * dw1[r];
        w1own += alpha * dOwn;
        nu += alpha * nu_d;
        WFENCE();   // keep next iteration's LDS writes behind this one's reads
    }

    // ---------------- epilogue: cost ----------------
    if (lane == 0) {
        #pragma unroll
        for (int r = 0; r < 10; ++r) wL[r] = w1[r];
    }
    __syncthreads();
    float part = a40 ? (w2a * w2a + w2b * w2b) : 0.f;
    for (int idx = lane; idx < 100; idx += 64) {
        const int r = idx / 10, c = idx - r * 10;
        part += wL[r] * QhL[r * 12 + c] * wL[c];
    }
    if (lane < 10) part += pvL[lane] * wL[lane];
    for (int idx = lane; idx < 160; idx += 64) {
        const int i2 = idx >> 4, rc = idx & 15, rr2 = rc >> 2, cc2 = rc & 3;
        part += axL[i2 * 4 + rr2] * QL[rc] * axL[i2 * 4 + cc2];
    }
    if (lane == 0) {
        float ct = 0.f;
        #pragma unroll
        for (int r = 0; r < 4; ++r) {
            const float xr = (r == 0 ? xv0 : r == 1 ? xv1 : r == 2 ? xv2 : xv3);
            #pragma unroll
            for (int c = 0; c < 4; ++c) {
                const float xc = (c == 0 ? xv0 : c == 1 ? xv1 : c == 2 ? xv2 : xv3);
                ct += xr * QL[r * 4 + c] * xc;
            }
        }
        part += ct;
    }
    const float cost = wave_sum(part);
    if (lane == 0) {
        out[item] = cost;
        out[BATCH + item] = w1[0];
    }
}

extern "C" void kernel_launch(void* const* d_in, const int* in_sizes, int n_in,
                              void* d_out, int out_size, void* d_ws, size_t ws_size,
                              hipStream_t stream) {
    const float* x  = (const float*)d_in[0];
    const float* u0 = (const float*)d_in[1];
    const float* Qs = (const float*)d_in[2];
    const float* Rs = (const float*)d_in[3];
    const float* Ad = (const float*)d_in[4];
    const float* Bd = (const float*)d_in[5];
    float* outp = (float*)d_out;
    ipm_kernel<<<dim3(BATCH), dim3(64), 0, stream>>>(x, u0, Qs, Rs, Ad, Bd, outp);
}

// Round 10
// 97.401 us; speedup vs baseline: 1.0239x; 1.0239x over previous
//
#include <hip/hip_runtime.h>

#define BATCH 1024
#define ITERS 20
#define SIGMA_C 0.1f
#define REG_C 1e-8f

typedef float f2 __attribute__((ext_vector_type(2)));

__device__ __forceinline__ float frcp(float x) { return __builtin_amdgcn_rcpf(x); }
__device__ __forceinline__ float readlane_f(float v, int l) {
    return __int_as_float(__builtin_amdgcn_readlane(__float_as_int(v), l));
}
__device__ __forceinline__ f2 mkf2(float a, float b) { f2 r; r.x = a; r.y = b; return r; }
// a*b+c on packed f32; fp-contract fuses to v_pk_fma_f32 (full-rate 2xFP32 on CDNA)
__device__ __forceinline__ f2 fma2(f2 a, f2 b, f2 c) { return a * b + c; }

// Single-wave workgroup: LDS ops from one wave are processed in order by the
// LDS pipe, so write->read RAW needs no s_barrier / full lgkmcnt(0) drain.
#define WFENCE() do { __builtin_amdgcn_wave_barrier(); asm volatile("" ::: "memory"); } while (0)

// DPP helpers: ctrl/mask must be literals
#define DPPF(v, ctrl) \
    __int_as_float(__builtin_amdgcn_update_dpp(0, __float_as_int(v), ctrl, 0xf, 0xf, true))
#define DPPB(v, ctrl, rmask) \
    __int_as_float(__builtin_amdgcn_update_dpp(0, __float_as_int(v), ctrl, rmask, 0xf, false))

__device__ __forceinline__ float wave_sum(float v) {   // full-broadcast version (cold paths)
    v += DPPF(v, 0xB1);
    v += DPPF(v, 0x4E);
    v += DPPF(v, 0x141);
    v += DPPF(v, 0x140);
    v += __shfl_xor(v, 16);
    v += __shfl_xor(v, 32);
    return v;
}

// fused 3-stream intra-row reduction step (2 sums + 1 max)
#define RED3_DPP(ctrl) do { \
    p1 += DPPF(p1, ctrl); \
    p2 += DPPF(p2, ctrl); \
    q = fmaxf(q, DPPF(q, ctrl)); \
} while (0)

// One wave (64 lanes) per batch item. Lane k<40 owns constraint rows
// {B:20+k, C:60+k, D:100+k, E:140+k} and e-vars w2a=w[10+k], w2b=w[50+k].
// Lanes<20 own the u-box rows. w1[10] replicated in all lanes.
// S-formation: lanes 10-59 own 2 adjacent S entries (register f2 tables);
// lanes 0-9 own rhs row `lane` IN-REGISTER (same lanes run the LU solve).
// In-loop reductions finish with DPP row_bcast15/31 + readlane(63) — no DS ops.
__global__ __launch_bounds__(64, 1) void ipm_kernel(
    const float* __restrict__ x, const float* __restrict__ u0p,
    const float* __restrict__ Qs, const float* __restrict__ Rs,
    const float* __restrict__ Ad, const float* __restrict__ Bd,
    float* __restrict__ out)
{
    const int item = blockIdx.x;
    const int lane = threadIdx.x;

    __shared__ __align__(16) float BLc[10 * 40];  // B column-major: BLc[j][k]=B[k][j]
    __shared__ __align__(16) float QBc[10 * 40];  // (Q_diag B) column-major
    __shared__ __align__(16) float yL4[40];
    __shared__ __align__(16) float QhL[10 * 12];
    __shared__ __align__(16) float SL[10 * 12];   // cols 0-9 = S
    __shared__ __align__(16) float cg[80];        // [0,40)=coeff, [40,80)=gvc
    __shared__ float duL[20], ltL[20];
    __shared__ float axL[40];
    __shared__ float pvL[10], wL[10];
    __shared__ float QL[16];
    __shared__ float TL[40];    // T[i][r] = (A^i B)[r]
    __shared__ float AhL[160];  // A_hat [40][4]

    // ---------------- prologue ----------------
    const int r2 = (lane >> 2) & 3, c2 = lane & 3;
    const int r4 = lane & 3;

    if (lane < 16) {
        float acc = 0.f;
        #pragma unroll
        for (int k = 0; k < 4; ++k) acc += Qs[r2 * 4 + k] * Qs[c2 * 4 + k];
        QL[lane] = acc;
    }

    // A powers -> A_hat (shfl chain)
    float acol[4];
    #pragma unroll
    for (int k = 0; k < 4; ++k) acol[k] = Ad[k * 4 + c2];
    float cur = Ad[r2 * 4 + c2];
    if (lane < 16) AhL[r2 * 4 + c2] = cur;
    #pragma unroll
    for (int i = 1; i < 10; ++i) {
        float nx = 0.f;
        #pragma unroll
        for (int k = 0; k < 4; ++k) nx += __shfl(cur, r2 * 4 + k) * acol[k];
        cur = nx;
        if (lane < 16) AhL[(4 * i + r2) * 4 + c2] = cur;
    }

    // T chain
    float arow[4];
    #pragma unroll
    for (int k = 0; k < 4; ++k) arow[k] = Ad[r4 * 4 + k];
    float tc = Bd[r4];
    if (lane < 4) TL[r4] = tc;
    #pragma unroll
    for (int i = 1; i < 10; ++i) {
        float nt = 0.f;
        #pragma unroll
        for (int k = 0; k < 4; ++k) nt += arow[k] * __shfl(tc, k);
        tc = nt;
        if (lane < 4) TL[i * 4 + r4] = nt;
    }
    __syncthreads();

    // per-lane B_hat row
    const int kk40 = (lane < 40) ? lane : 39;
    const int ib = lane >> 2;
    float b[10];
    #pragma unroll
    for (int j = 0; j < 10; ++j) {
        int dd = ib - j;
        int dc = dd < 0 ? 0 : (dd > 9 ? 9 : dd);
        float v = TL[dc * 4 + r4];
        b[j] = (dd >= 0 && lane < 40) ? v : 0.f;
    }

    const float xv0 = x[item * 4 + 0], xv1 = x[item * 4 + 1];
    const float xv2 = x[item * 4 + 2], xv3 = x[item * 4 + 3];
    const float ax = AhL[kk40 * 4 + 0] * xv0 + AhL[kk40 * 4 + 1] * xv1 +
                     AhL[kk40 * 4 + 2] * xv2 + AhL[kk40 * 4 + 3] * xv3;
    if (lane < 40) axL[lane] = ax;

    const int gbase = lane & ~3;
    float yv = 0.f;
    #pragma unroll
    for (int rp_ = 0; rp_ < 4; ++rp_) yv += QL[r4 * 4 + rp_] * __shfl(ax, gbase + rp_);
    if (lane < 40) yL4[lane] = yv;
    #pragma unroll
    for (int cc = 0; cc < 10; ++cc) {
        float acc = 0.f;
        #pragma unroll
        for (int rp_ = 0; rp_ < 4; ++rp_) acc += QL[r4 * 4 + rp_] * __shfl(b[cc], gbase + rp_);
        if (lane < 40) QBc[cc * 40 + lane] = acc;
    }
    if (lane < 40) {
        #pragma unroll
        for (int j = 0; j < 10; ++j) BLc[j * 40 + lane] = b[j];
    }
    __syncthreads();

    // pv (lanes 0-9)
    if (lane < 10) {
        const float4* br = reinterpret_cast<const float4*>(&BLc[lane * 40]);
        const float4* yy = reinterpret_cast<const float4*>(yL4);
        float acc = 0.f;
        #pragma unroll
        for (int i = 0; i < 10; ++i) {
            const float4 a_ = br[i], b_ = yy[i];
            acc += a_.x * b_.x + a_.y * b_.y + a_.z * b_.z + a_.w * b_.w;
        }
        pvL[lane] = 2.f * acc;
    }
    // Qh (100 tasks)
    const float R2v = Rs[0] * Rs[0];
    #pragma unroll
    for (int p = 0; p < 2; ++p) {
        const int t = lane + 64 * p;
        if (t < 100) {
            const int aa = t / 10, bb = t - aa * 10;
            const float4* ba = reinterpret_cast<const float4*>(&BLc[aa * 40]);
            const float4* qb = reinterpret_cast<const float4*>(&QBc[bb * 40]);
            float acc = (aa == bb) ? R2v : 0.f;
            #pragma unroll
            for (int i = 0; i < 10; ++i) {
                const float4 a_ = ba[i], b_ = qb[i];
                acc += a_.x * b_.x + a_.y * b_.y + a_.z * b_.z + a_.w * b_.w;
            }
            QhL[aa * 12 + bb] = acc;
        }
    }
    __syncthreads();

    // ---------------- per-lane register task caches (packed f2) ----------------
    const bool rLane = (lane < 10);                  // rhs producers == solve rows
    const bool sLane = (lane >= 10 && lane < 60);    // S-entry pairs
    const int t1 = sLane ? 2 * (lane - 10) : 0;
    const int srow = t1 / 10, sc1 = t1 - srow * 10, sc2 = sc1 + 1;
    f2 tA[20], tB[20];
    float qh_a = 0.f, qh_b = 0.f;
    bool diagA = false, diagB = false;
    if (sLane) {
        const float4* br = reinterpret_cast<const float4*>(&BLc[srow * 40]);
        const float4* b1 = reinterpret_cast<const float4*>(&BLc[sc1 * 40]);
        const float4* b2 = reinterpret_cast<const float4*>(&BLc[sc2 * 40]);
        #pragma unroll
        for (int i = 0; i < 10; ++i) {
            const float4 r_ = br[i], u_ = b1[i], v_ = b2[i];
            tA[2*i]   = mkf2(r_.x * u_.x, r_.y * u_.y);
            tA[2*i+1] = mkf2(r_.z * u_.z, r_.w * u_.w);
            tB[2*i]   = mkf2(r_.x * v_.x, r_.y * v_.y);
            tB[2*i+1] = mkf2(r_.z * v_.z, r_.w * v_.w);
        }
        qh_a = 2.f * QhL[srow * 12 + sc1];
        qh_b = 2.f * QhL[srow * 12 + sc2];
        diagA = (srow == sc1); diagB = (srow == sc2);
    } else if (rLane) {
        const float4* br = reinterpret_cast<const float4*>(&BLc[lane * 40]);
        #pragma unroll
        for (int i = 0; i < 10; ++i) {
            const float4 r_ = br[i];
            tA[2*i]   = mkf2(r_.x, r_.y);
            tA[2*i+1] = mkf2(r_.z, r_.w);
        }
        #pragma unroll
        for (int c = 0; c < 5; ++c)
            tB[c] = mkf2(QhL[lane * 12 + 2*c], QhL[lane * 12 + 2*c + 1]);
        qh_a = pvL[lane];
    }
    __syncthreads();

    // ---------------- state init ----------------
    float s_B = fmaxf(4.f - ax, 1.f), s_C = fmaxf(4.f + ax, 1.f);
    float s_D = 1.f, s_E = 1.f, s_U = 1.f;
    float l_B = 1.f, l_C = 1.f, l_D = 1.f, l_E = 1.f, l_U = 1.f;
    float w2a = 0.f, w2b = 0.f;
    float w1[10];
    #pragma unroll
    for (int r = 0; r < 10; ++r) w1[r] = 0.f;
    float w1own = 0.f, nu = 0.f;
    float Bu = 0.f;      // running b . w1   (w1 starts at 0)
    float qwr = 0.f;     // running Qh_row . w1 (rhs lanes)
    const float uu0 = u0p[item];
    const bool a40 = lane < 40, a20 = lane < 20;
    const int jown = (lane < 10) ? lane : lane - 10;
    const float sgnU = (lane < 10) ? 1.f : -1.f;

    // initial mu = SIGMA * sum(s*l)/180 (one-time; thereafter via alpha-polynomial)
    float mu;
    {
        float part = a40 ? (s_B * l_B + s_C * l_C + s_D * l_D + s_E * l_E) : 0.f;
        if (a20) part += s_U * l_U;
        mu = SIGMA_C * wave_sum(part) * (1.f / 180.f);
    }

    // ---------------- IPM iterations ----------------
    for (int it = 0; it < ITERS; ++it) {
        const float rs_B = frcp(s_B), rs_C = frcp(s_C), rs_D = frcp(s_D),
                    rs_E = frcp(s_E), rs_U = frcp(s_U);
        const float rl_B = frcp(l_B), rl_C = frcp(l_C), rl_D = frcp(l_D),
                    rl_E = frcp(l_E), rl_U = frcp(l_U);
        const float d_B = l_B * rs_B, d_C = l_C * rs_C, d_D = l_D * rs_D,
                    d_E = l_E * rs_E, d_U = l_U * rs_U;

        const float rp_B = Bu - w2a + s_B - (4.f - ax);
        const float rp_C = -Bu - w2b + s_C - (4.f + ax);
        const float rp_D = -w2a + s_D;
        const float rp_E = -w2b + s_E;
        const float rp_U = sgnU * w1own + s_U - 0.5f;

        const float tm_B = (mu - l_B * s_B + l_B * rp_B) * rs_B;
        const float tm_C = (mu - l_C * s_C + l_C * rp_C) * rs_C;
        const float tm_D = (mu - l_D * s_D + l_D * rp_D) * rs_D;
        const float tm_E = (mu - l_E * s_E + l_E * rp_E) * rs_E;
        const float tm_U = (mu - l_U * s_U + l_U * rp_U) * rs_U;
        const float lt_B = l_B + tm_B, lt_C = l_C + tm_C, lt_D = l_D + tm_D,
                    lt_E = l_E + tm_E;

        const float D22a = 2.f + d_B + d_D + REG_C, D22b = 2.f + d_C + d_E + REG_C;
        const float rda = frcp(D22a), rdb = frcp(D22b);
        const float rw2a = -2.f * w2a + lt_B + lt_D;
        const float rw2b = -2.f * w2b + lt_C + lt_E;
        const float coeff = (d_B + d_C) - d_B * d_B * rda - d_C * d_C * rdb;
        const float gvc = (d_B * rw2a * rda - d_C * rw2b * rdb) - (lt_B - lt_C);

        if (a40) { cg[lane] = coeff; cg[40 + lane] = gvc; }
        if (a20) { duL[lane] = d_U; ltL[lane] = l_U + tm_U; }
        WFENCE();   // single wave: in-order DS pipe makes RAW safe without barrier

        // ---- cf loads issued immediately (pipeline behind the writes) ----
        float4 cf4[10];
        {
            const float4* cp = reinterpret_cast<const float4*>(cg + (rLane ? 40 : 0));
            #pragma unroll
            for (int i = 0; i < 10; ++i) cf4[i] = cp[i];
        }

        // ---- p0 = sum(s*l) reduction in the load shadow (DPP bcast tail) ----
        float p0 = a40 ? (s_B * l_B + s_C * l_C + s_D * l_D + s_E * l_E) : 0.f;
        if (a20) p0 += s_U * l_U;
        p0 += DPPF(p0, 0xB1);
        p0 += DPPF(p0, 0x4E);
        p0 += DPPF(p0, 0x141);
        p0 += DPPF(p0, 0x140);
        p0 += DPPB(p0, 0x142, 0xA);   // row_bcast15 into rows 1,3
        p0 += DPPB(p0, 0x143, 0xC);   // row_bcast31 into rows 2,3
        const float p0T = readlane_f(p0, 63);

        // ---- S + rhs formation (packed-f2 register tables) ----
        float rhs_loc = 0.f;
        if (sLane) {
            f2 aA0 = mkf2(0.f, 0.f), aA1 = mkf2(0.f, 0.f);
            f2 aB0 = mkf2(0.f, 0.f), aB1 = mkf2(0.f, 0.f);
            #pragma unroll
            for (int i = 0; i < 10; ++i) {
                const f2 cl = mkf2(cf4[i].x, cf4[i].y);
                const f2 ch = mkf2(cf4[i].z, cf4[i].w);
                aA0 = fma2(tA[2*i], cl, aA0); aA1 = fma2(tA[2*i+1], ch, aA1);
                aB0 = fma2(tB[2*i], cl, aB0); aB1 = fma2(tB[2*i+1], ch, aB1);
            }
            float vA = ((aA0.x + aA0.y) + (aA1.x + aA1.y)) + qh_a;
            float vB = ((aB0.x + aB0.y) + (aB1.x + aB1.y)) + qh_b;
            if (diagA || diagB) {
                const float dd = duL[srow] + duL[10 + srow] + REG_C;
                if (diagA) vA += dd; else vB += dd;
            }
            *reinterpret_cast<float2*>(&SL[srow * 12 + sc1]) = make_float2(vA, vB);
        } else if (rLane) {
            f2 a0 = mkf2(0.f, 0.f), a1 = mkf2(0.f, 0.f);
            #pragma unroll
            for (int i = 0; i < 10; ++i) {
                const f2 cl = mkf2(cf4[i].x, cf4[i].y);
                const f2 ch = mkf2(cf4[i].z, cf4[i].w);
                a0 = fma2(tA[2*i], cl, a0); a1 = fma2(tA[2*i+1], ch, a1);
            }
            const float acc = (a0.x + a0.y) + (a1.x + a1.y);
            // qwr = Qh_row . w1 maintained incrementally (no dot here)
            rhs_loc = acc - (2.f * qwr + qh_a + ltL[lane] - ltL[10 + lane] +
                             ((lane == 0) ? nu : 0.f));
        }
        WFENCE();   // SL stores (lanes 10-59) ordered before SL reads (lanes 0-9)

        // ---- LU solve: rows on lanes 0-9; rhs LOCAL; pivot rcp prefetched ----
        float row[11], rBv;
        if (rLane) {
            const float4* s4 = reinterpret_cast<const float4*>(&SL[lane * 12]);
            const float4 q0 = s4[0], q1 = s4[1], q2 = s4[2];
            row[0] = q0.x; row[1] = q0.y; row[2] = q0.z; row[3] = q0.w;
            row[4] = q1.x; row[5] = q1.y; row[6] = q1.z; row[7] = q1.w;
            row[8] = q2.x; row[9] = q2.y;
        } else {
            #pragma unroll
            for (int c = 0; c < 10; ++c) row[c] = 0.f;
        }
        row[10] = rhs_loc;
        rBv = (lane == 0) ? 1.f : 0.f;

        float rd[10];            // rd[r] = frcp(own row[r]); filled as pivots finalize
        rd[0] = frcp(row[0]);
        #pragma unroll
        for (int kc = 0; kc < 9; ++kc) {
            float pk[11];
            #pragma unroll
            for (int c = kc + 1; c < 11; ++c) pk[c] = readlane_f(row[c], kc);
            const float pB = readlane_f(rBv, kc);
            const float rpiv = readlane_f(rd[kc], kc);   // prefetched reciprocal
            const float f = (lane > kc) ? row[kc] * rpiv : 0.f;
            #pragma unroll
            for (int c = kc + 1; c < 11; ++c) row[c] -= f * pk[c];
            rBv -= f * pB;
            rd[kc + 1] = frcp(row[kc + 1]);              // next pivot's rcp, off-chain
        }

        float dwAv[10], dwBv[10], ownA = 0.f, ownB = 0.f;
        #pragma unroll
        for (int r = 9; r >= 0; --r) {
            const float bA = readlane_f(row[10] * rd[r], r);
            const float bB = readlane_f(rBv * rd[r], r);
            dwAv[r] = bA; dwBv[r] = bB;
            if (jown == r) { ownA = bA; ownB = bB; }
            const float m_ = (lane < r) ? 1.f : 0.f;
            row[10] -= m_ * row[r] * bA;
            rBv     -= m_ * row[r] * bB;
        }

        const float rn = -(w1[0] - uu0);
        const float nu_d = (dwAv[0] - rn) * frcp(dwBv[0] + REG_C);
        float dw1[10];
        #pragma unroll
        for (int r = 0; r < 10; ++r) dw1[r] = dwAv[r] - nu_d * dwBv[r];
        const float dOwn = ownA - nu_d * ownB;

        f2 bd = mkf2(0.f, 0.f), qd = mkf2(0.f, 0.f);
        #pragma unroll
        for (int j = 0; j < 5; ++j) {
            const f2 dv = mkf2(dw1[2*j], dw1[2*j+1]);
            bd = fma2(mkf2(b[2*j], b[2*j+1]), dv, bd);
            qd = fma2(tB[j], dv, qd);            // Qh_row . dw1 (rhs lanes)
        }
        const float Bdw = bd.x + bd.y;
        const float qdw = qd.x + qd.y;

        const float dw2a = (rw2a + d_B * Bdw) * rda;
        const float dw2b = (rw2b - d_C * Bdw) * rdb;

        const float ds_B = -(Bdw - dw2a) - rp_B;
        const float ds_C = (Bdw + dw2b) - rp_C;
        const float ds_D = dw2a - rp_D;
        const float ds_E = dw2b - rp_E;
        const float ds_U = -sgnU * dOwn - rp_U;
        const float dl_B = (mu - l_B * s_B - l_B * ds_B) * rs_B;
        const float dl_C = (mu - l_C * s_C - l_C * ds_C) * rs_C;
        const float dl_D = (mu - l_D * s_D - l_D * ds_D) * rs_D;
        const float dl_E = (mu - l_E * s_E - l_E * ds_E) * rs_E;
        const float dl_U = (mu - l_U * s_U - l_U * ds_U) * rs_U;

        // ---- step ratios via q = max((-dv)*(1/v)); DPP bcast tail, no DS ----
        float q = 0.f, p1 = 0.f, p2 = 0.f;
        if (a40) {
            q = fmaxf(q, (ds_B < -1e-12f) ? -ds_B * rs_B : 0.f);
            q = fmaxf(q, (ds_C < -1e-12f) ? -ds_C * rs_C : 0.f);
            q = fmaxf(q, (ds_D < -1e-12f) ? -ds_D * rs_D : 0.f);
            q = fmaxf(q, (ds_E < -1e-12f) ? -ds_E * rs_E : 0.f);
            q = fmaxf(q, (dl_B < -1e-12f) ? -dl_B * rl_B : 0.f);
            q = fmaxf(q, (dl_C < -1e-12f) ? -dl_C * rl_C : 0.f);
            q = fmaxf(q, (dl_D < -1e-12f) ? -dl_D * rl_D : 0.f);
            q = fmaxf(q, (dl_E < -1e-12f) ? -dl_E * rl_E : 0.f);
            p1 = (s_B * dl_B + l_B * ds_B) + (s_C * dl_C + l_C * ds_C) +
                 (s_D * dl_D + l_D * ds_D) + (s_E * dl_E + l_E * ds_E);
            p2 = ds_B * dl_B + ds_C * dl_C + ds_D * dl_D + ds_E * dl_E;
        }
        if (a20) {
            q = fmaxf(q, (ds_U < -1e-12f) ? -ds_U * rs_U : 0.f);
            q = fmaxf(q, (dl_U < -1e-12f) ? -dl_U * rl_U : 0.f);
            p1 += s_U * dl_U + l_U * ds_U;
            p2 += ds_U * dl_U;
        }
        RED3_DPP(0xB1);
        RED3_DPP(0x4E);
        RED3_DPP(0x141);
        RED3_DPP(0x140);
        p1 += DPPB(p1, 0x142, 0xA); p2 += DPPB(p2, 0x142, 0xA);
        q = fmaxf(q, DPPB(q, 0x142, 0xA));
        p1 += DPPB(p1, 0x143, 0xC); p2 += DPPB(p2, 0x143, 0xC);
        q = fmaxf(q, DPPB(q, 0x143, 0xC));
        const float qT  = readlane_f(q, 63);
        const float p1T = readlane_f(p1, 63);
        const float p2T = readlane_f(p2, 63);

        const float alpha = 0.99f * frcp(fmaxf(qT, 1.f));   // frcp(1)=1 exact
        mu = SIGMA_C * (p0T + alpha * (p1T + alpha * p2T)) * (1.f / 180.f);

        s_B += alpha * ds_B; s_C += alpha * ds_C; s_D += alpha * ds_D;
        s_E += alpha * ds_E; s_U += alpha * ds_U;
        l_B += alpha * dl_B; l_C += alpha * dl_C; l_D += alpha * dl_D;
        l_E += alpha * dl_E; l_U += alpha * dl_U;
        w2a += alpha * dw2a; w2b += alpha * dw2b;
        #pragma unroll
        for (int r = 0; r < 10; ++r) w1[r] += alpha * dw1[r];
        w1own += alpha * dOwn;
        nu += alpha * nu_d;
        Bu  += alpha * Bdw;     // incremental b . w1
        qwr += alpha * qdw;     // incremental Qh_row . w1
        WFENCE();   // keep next iteration's LDS writes behind this one's reads
    }

    // ---------------- epilogue: cost ----------------
    if (lane == 0) {
        #pragma unroll
        for (int r = 0; r < 10; ++r) wL[r] = w1[r];
    }
    __syncthreads();
    float part = a40 ? (w2a * w2a + w2b * w2b) : 0.f;
    for (int idx = lane; idx < 100; idx += 64) {
        const int r = idx / 10, c = idx - r * 10;
        part += wL[r] * QhL[r * 12 + c] * wL[c];
    }
    if (lane < 10) part += pvL[lane] * wL[lane];
    for (int idx = lane; idx < 160; idx += 64) {
        const int i2 = idx >> 4, rc = idx & 15, rr2 = rc >> 2, cc2 = rc & 3;
        part += axL[i2 * 4 + rr2] * QL[rc] * axL[i2 * 4 + cc2];
    }
    if (lane == 0) {
        float ct = 0.f;
        #pragma unroll
        for (int r = 0; r < 4; ++r) {
            const float xr = (r == 0 ? xv0 : r == 1 ? xv1 : r == 2 ? xv2 : xv3);
            #pragma unroll
            for (int c = 0; c < 4; ++c) {
                const float xc = (c == 0 ? xv0 : c == 1 ? xv1 : c == 2 ? xv2 : xv3);
                ct += xr * QL[r * 4 + c] * xc;
            }
        }
        part += ct;
    }
    const float cost = wave_sum(part);
    if (lane == 0) {
        out[item] = cost;
        out[BATCH + item] = w1[0];
    }
}

extern "C" void kernel_launch(void* const* d_in, const int* in_sizes, int n_in,
                              void* d_out, int out_size, void* d_ws, size_t ws_size,
                              hipStream_t stream) {
    const float* x  = (const float*)d_in[0];
    const float* u0 = (const float*)d_in[1];
    const float* Qs = (const float*)d_in[2];
    const float* Rs = (const float*)d_in[3];
    const float* Ad = (const float*)d_in[4];
    const float* Bd = (const float*)d_in[5];
    float* outp = (float*)d_out;
    ipm_kernel<<<dim3(BATCH), dim3(64), 0, stream>>>(x, u0, Qs, Rs, Ad, Bd, outp);
}

// Round 11
// 94.056 us; speedup vs baseline: 1.0603x; 1.0356x over previous
//
#include <hip/hip_runtime.h>

#define BATCH 1024
#define ITERS 20
#define SIGMA_C 0.1f
#define REG_C 1e-8f

typedef float f2 __attribute__((ext_vector_type(2)));

__device__ __forceinline__ float frcp(float x) { return __builtin_amdgcn_rcpf(x); }
__device__ __forceinline__ float readlane_f(float v, int l) {
    return __int_as_float(__builtin_amdgcn_readlane(__float_as_int(v), l));
}
__device__ __forceinline__ f2 mkf2(float a, float b) { f2 r; r.x = a; r.y = b; return r; }
__device__ __forceinline__ f2 fma2(f2 a, f2 b, f2 c) { return a * b + c; }   // v_pk_fma_f32
__device__ __forceinline__ f2 max2(f2 a, f2 b) { return mkf2(fmaxf(a.x, b.x), fmaxf(a.y, b.y)); }
__device__ __forceinline__ f2 rcp2(f2 a) { return mkf2(frcp(a.x), frcp(a.y)); }

// Single-wave workgroup: LDS ops from one wave are processed in order by the
// LDS pipe, so write->read RAW needs no s_barrier / full lgkmcnt(0) drain.
#define WFENCE() do { __builtin_amdgcn_wave_barrier(); asm volatile("" ::: "memory"); } while (0)

// DPP helpers: ctrl/mask must be literals
#define DPPF(v, ctrl) \
    __int_as_float(__builtin_amdgcn_update_dpp(0, __float_as_int(v), ctrl, 0xf, 0xf, true))
#define DPPB(v, ctrl, rmask) \
    __int_as_float(__builtin_amdgcn_update_dpp(0, __float_as_int(v), ctrl, rmask, 0xf, false))

__device__ __forceinline__ float wave_sum(float v) {   // full-broadcast version (cold paths)
    v += DPPF(v, 0xB1);
    v += DPPF(v, 0x4E);
    v += DPPF(v, 0x141);
    v += DPPF(v, 0x140);
    v += __shfl_xor(v, 16);
    v += __shfl_xor(v, 32);
    return v;
}

// fused 3-stream intra-row reduction step (2 sums + 1 max)
#define RED3_DPP(ctrl) do { \
    p1 += DPPF(p1, ctrl); \
    p2 += DPPF(p2, ctrl); \
    q = fmaxf(q, DPPF(q, ctrl)); \
} while (0)

// One wave (64 lanes) per batch item. Lane k<40 owns constraint rows
// {B:20+k, C:60+k, D:100+k, E:140+k} packed as f2 pairs (B,C) and (D,E),
// plus e-vars w2=(w[10+k], w[50+k]). Lanes<20 own the u-box rows.
// w1[10] replicated. S-formation: lanes 10-59 own 2 adjacent S entries;
// lanes 0-9 own rhs row `lane` in-register (same lanes run the LU solve).
__global__ __launch_bounds__(64, 1) void ipm_kernel(
    const float* __restrict__ x, const float* __restrict__ u0p,
    const float* __restrict__ Qs, const float* __restrict__ Rs,
    const float* __restrict__ Ad, const float* __restrict__ Bd,
    float* __restrict__ out)
{
    const int item = blockIdx.x;
    const int lane = threadIdx.x;

    __shared__ __align__(16) float BLc[10 * 40];  // B column-major: BLc[j][k]=B[k][j]
    __shared__ __align__(16) float QBc[10 * 40];  // (Q_diag B) column-major
    __shared__ __align__(16) float yL4[40];
    __shared__ __align__(16) float QhL[10 * 12];
    __shared__ __align__(16) float SL[10 * 12];   // cols 0-9 = S
    __shared__ __align__(16) float cg[80];        // [0,40)=coeff, [40,80)=gvc
    __shared__ float duL[20], ltL[20];
    __shared__ float axL[40];
    __shared__ float pvL[10], wL[10];
    __shared__ float QL[16];
    __shared__ float TL[40];    // T[i][r] = (A^i B)[r]
    __shared__ float AhL[160];  // A_hat [40][4]

    // ---------------- prologue ----------------
    const int r2 = (lane >> 2) & 3, c2 = lane & 3;
    const int r4 = lane & 3;

    if (lane < 16) {
        float acc = 0.f;
        #pragma unroll
        for (int k = 0; k < 4; ++k) acc += Qs[r2 * 4 + k] * Qs[c2 * 4 + k];
        QL[lane] = acc;
    }

    // A powers -> A_hat (shfl chain)
    float acol[4];
    #pragma unroll
    for (int k = 0; k < 4; ++k) acol[k] = Ad[k * 4 + c2];
    float cur = Ad[r2 * 4 + c2];
    if (lane < 16) AhL[r2 * 4 + c2] = cur;
    #pragma unroll
    for (int i = 1; i < 10; ++i) {
        float nx = 0.f;
        #pragma unroll
        for (int k = 0; k < 4; ++k) nx += __shfl(cur, r2 * 4 + k) * acol[k];
        cur = nx;
        if (lane < 16) AhL[(4 * i + r2) * 4 + c2] = cur;
    }

    // T chain
    float arow[4];
    #pragma unroll
    for (int k = 0; k < 4; ++k) arow[k] = Ad[r4 * 4 + k];
    float tc = Bd[r4];
    if (lane < 4) TL[r4] = tc;
    #pragma unroll
    for (int i = 1; i < 10; ++i) {
        float nt = 0.f;
        #pragma unroll
        for (int k = 0; k < 4; ++k) nt += arow[k] * __shfl(tc, k);
        tc = nt;
        if (lane < 4) TL[i * 4 + r4] = nt;
    }
    __syncthreads();

    // per-lane B_hat row
    const int kk40 = (lane < 40) ? lane : 39;
    const int ib = lane >> 2;
    float b[10];
    #pragma unroll
    for (int j = 0; j < 10; ++j) {
        int dd = ib - j;
        int dc = dd < 0 ? 0 : (dd > 9 ? 9 : dd);
        float v = TL[dc * 4 + r4];
        b[j] = (dd >= 0 && lane < 40) ? v : 0.f;
    }

    const float xv0 = x[item * 4 + 0], xv1 = x[item * 4 + 1];
    const float xv2 = x[item * 4 + 2], xv3 = x[item * 4 + 3];
    const float ax = AhL[kk40 * 4 + 0] * xv0 + AhL[kk40 * 4 + 1] * xv1 +
                     AhL[kk40 * 4 + 2] * xv2 + AhL[kk40 * 4 + 3] * xv3;
    if (lane < 40) axL[lane] = ax;

    const int gbase = lane & ~3;
    float yv = 0.f;
    #pragma unroll
    for (int rp_ = 0; rp_ < 4; ++rp_) yv += QL[r4 * 4 + rp_] * __shfl(ax, gbase + rp_);
    if (lane < 40) yL4[lane] = yv;
    #pragma unroll
    for (int cc = 0; cc < 10; ++cc) {
        float acc = 0.f;
        #pragma unroll
        for (int rp_ = 0; rp_ < 4; ++rp_) acc += QL[r4 * 4 + rp_] * __shfl(b[cc], gbase + rp_);
        if (lane < 40) QBc[cc * 40 + lane] = acc;
    }
    if (lane < 40) {
        #pragma unroll
        for (int j = 0; j < 10; ++j) BLc[j * 40 + lane] = b[j];
    }
    __syncthreads();

    // pv (lanes 0-9)
    if (lane < 10) {
        const float4* br = reinterpret_cast<const float4*>(&BLc[lane * 40]);
        const float4* yy = reinterpret_cast<const float4*>(yL4);
        float acc = 0.f;
        #pragma unroll
        for (int i = 0; i < 10; ++i) {
            const float4 a_ = br[i], b_ = yy[i];
            acc += a_.x * b_.x + a_.y * b_.y + a_.z * b_.z + a_.w * b_.w;
        }
        pvL[lane] = 2.f * acc;
    }
    // Qh (100 tasks)
    const float R2v = Rs[0] * Rs[0];
    #pragma unroll
    for (int p = 0; p < 2; ++p) {
        const int t = lane + 64 * p;
        if (t < 100) {
            const int aa = t / 10, bb = t - aa * 10;
            const float4* ba = reinterpret_cast<const float4*>(&BLc[aa * 40]);
            const float4* qb = reinterpret_cast<const float4*>(&QBc[bb * 40]);
            float acc = (aa == bb) ? R2v : 0.f;
            #pragma unroll
            for (int i = 0; i < 10; ++i) {
                const float4 a_ = ba[i], b_ = qb[i];
                acc += a_.x * b_.x + a_.y * b_.y + a_.z * b_.z + a_.w * b_.w;
            }
            QhL[aa * 12 + bb] = acc;
        }
    }
    __syncthreads();

    // ---------------- per-lane register task caches (packed f2) ----------------
    const bool rLane = (lane < 10);                  // rhs producers == solve rows
    const bool sLane = (lane >= 10 && lane < 60);    // S-entry pairs
    const int t1 = sLane ? 2 * (lane - 10) : 0;
    const int srow = t1 / 10, sc1 = t1 - srow * 10, sc2 = sc1 + 1;
    f2 tA[20], tB[20];
    #pragma unroll
    for (int i = 0; i < 20; ++i) { tA[i] = mkf2(0.f, 0.f); tB[i] = mkf2(0.f, 0.f); }
    float qh_a = 0.f, qh_b = 0.f;
    bool diagA = false, diagB = false;
    if (sLane) {
        const float4* br = reinterpret_cast<const float4*>(&BLc[srow * 40]);
        const float4* b1 = reinterpret_cast<const float4*>(&BLc[sc1 * 40]);
        const float4* b2 = reinterpret_cast<const float4*>(&BLc[sc2 * 40]);
        #pragma unroll
        for (int i = 0; i < 10; ++i) {
            const float4 r_ = br[i], u_ = b1[i], v_ = b2[i];
            tA[2*i]   = mkf2(r_.x * u_.x, r_.y * u_.y);
            tA[2*i+1] = mkf2(r_.z * u_.z, r_.w * u_.w);
            tB[2*i]   = mkf2(r_.x * v_.x, r_.y * v_.y);
            tB[2*i+1] = mkf2(r_.z * v_.z, r_.w * v_.w);
        }
        qh_a = 2.f * QhL[srow * 12 + sc1];
        qh_b = 2.f * QhL[srow * 12 + sc2];
        diagA = (srow == sc1); diagB = (srow == sc2);
    } else if (rLane) {
        const float4* br = reinterpret_cast<const float4*>(&BLc[lane * 40]);
        #pragma unroll
        for (int i = 0; i < 10; ++i) {
            const float4 r_ = br[i];
            tA[2*i]   = mkf2(r_.x, r_.y);
            tA[2*i+1] = mkf2(r_.z, r_.w);
        }
        #pragma unroll
        for (int c = 0; c < 5; ++c)
            tB[c] = mkf2(QhL[lane * 12 + 2*c], QhL[lane * 12 + 2*c + 1]);
        qh_a = pvL[lane];
    }
    __syncthreads();

    // ---------------- state init (f2-packed: x=B, y=C / x=D, y=E) ----------------
    const f2 hBC = mkf2(4.f - ax, 4.f + ax);
    const f2 sgnP = mkf2(1.f, -1.f);
    f2 s_BC = mkf2(fmaxf(hBC.x, 1.f), fmaxf(hBC.y, 1.f));
    f2 s_DE = mkf2(1.f, 1.f);
    f2 l_BC = mkf2(1.f, 1.f), l_DE = mkf2(1.f, 1.f);
    float s_U = 1.f, l_U = 1.f;
    f2 w2 = mkf2(0.f, 0.f);
    float w1[10];
    #pragma unroll
    for (int r = 0; r < 10; ++r) w1[r] = 0.f;
    float w1own = 0.f, nu = 0.f;
    float Bu = 0.f;      // running b . w1
    float qwr = 0.f;     // running Qh_row . w1 (rhs lanes)
    const float uu0 = u0p[item];
    const bool a40 = lane < 40, a20 = lane < 20;
    const int jown = (lane < 10) ? lane : lane - 10;
    const float sgnU = (lane < 10) ? 1.f : -1.f;

    // initial mu = SIGMA * sum(s*l)/180 (l == 1)
    float mu;
    {
        float part = a40 ? (s_BC.x + s_BC.y + s_DE.x + s_DE.y) : 0.f;
        if (a20) part += s_U;
        mu = SIGMA_C * wave_sum(part) * (1.f / 180.f);
    }

    // ---------------- IPM iterations ----------------
    for (int it = 0; it < ITERS; ++it) {
        const f2 rs_BC = rcp2(s_BC), rs_DE = rcp2(s_DE);
        const f2 rl_BC = rcp2(l_BC), rl_DE = rcp2(l_DE);
        const float rs_U = frcp(s_U), rl_U = frcp(l_U);
        const f2 d_BC = l_BC * rs_BC, d_DE = l_DE * rs_DE;
        const float d_U = l_U * rs_U;

        // residuals (packed)
        const f2 gw = sgnP * Bu - w2;            // (Bu - w2a, -Bu - w2b)
        const f2 rp_BC = gw + s_BC - hBC;
        const f2 rp_DE = s_DE - w2;
        const float rp_U = sgnU * w1own + s_U - 0.5f;

        const f2 mu2 = mkf2(mu, mu);
        const f2 tm_BC = (mu2 - l_BC * (s_BC - rp_BC)) * rs_BC;
        const f2 tm_DE = (mu2 - l_DE * (s_DE - rp_DE)) * rs_DE;
        const float tm_U = (mu - l_U * (s_U - rp_U)) * rs_U;
        const f2 lt_BC = l_BC + tm_BC, lt_DE = l_DE + tm_DE;

        const f2 D22 = d_BC + d_DE + mkf2(2.f + REG_C, 2.f + REG_C);  // (D22a, D22b)
        const f2 rdD = rcp2(D22);
        const f2 rw2 = lt_BC + lt_DE - 2.f * w2;                      // (rw2a, rw2b)
        const float coeff = (d_BC.x + d_BC.y) - d_BC.x * d_BC.x * rdD.x
                                              - d_BC.y * d_BC.y * rdD.y;
        const float gvc = (d_BC.x * rw2.x * rdD.x - d_BC.y * rw2.y * rdD.y)
                          - (lt_BC.x - lt_BC.y);

        if (a40) { cg[lane] = coeff; cg[40 + lane] = gvc; }
        if (a20) { duL[lane] = d_U; ltL[lane] = l_U + tm_U; }
        WFENCE();   // single wave: in-order DS pipe makes RAW safe without barrier

        // ---- cf loads issued immediately (pipeline behind the writes) ----
        float4 cf4[10];
        {
            const float4* cp = reinterpret_cast<const float4*>(cg + (rLane ? 40 : 0));
            #pragma unroll
            for (int i = 0; i < 10; ++i) cf4[i] = cp[i];
        }

        // ---- p0 = sum(s*l) reduction in the load shadow (DPP bcast tail) ----
        f2 pp0 = fma2(s_BC, l_BC, s_DE * l_DE);
        float p0 = a40 ? (pp0.x + pp0.y) : 0.f;
        if (a20) p0 += s_U * l_U;
        p0 += DPPF(p0, 0xB1);
        p0 += DPPF(p0, 0x4E);
        p0 += DPPF(p0, 0x141);
        p0 += DPPF(p0, 0x140);
        p0 += DPPB(p0, 0x142, 0xA);   // row_bcast15 into rows 1,3
        p0 += DPPB(p0, 0x143, 0xC);   // row_bcast31 into rows 2,3
        const float p0T = readlane_f(p0, 63);

        // ---- unified dot loops (identical shape for S-lanes and rhs-lanes) ----
        f2 aA0 = mkf2(0.f, 0.f), aA1 = mkf2(0.f, 0.f);
        f2 aB0 = mkf2(0.f, 0.f), aB1 = mkf2(0.f, 0.f);
        #pragma unroll
        for (int i = 0; i < 10; ++i) {
            const f2 cl = mkf2(cf4[i].x, cf4[i].y);
            const f2 ch = mkf2(cf4[i].z, cf4[i].w);
            aA0 = fma2(tA[2*i], cl, aA0); aA1 = fma2(tA[2*i+1], ch, aA1);
            aB0 = fma2(tB[2*i], cl, aB0); aB1 = fma2(tB[2*i+1], ch, aB1);
        }
        const float accA = (aA0.x + aA0.y) + (aA1.x + aA1.y);
        const float accB = (aB0.x + aB0.y) + (aB1.x + aB1.y);

        float rhs_loc = 0.f;
        if (sLane) {
            float vA = accA + qh_a, vB = accB + qh_b;
            if (diagA || diagB) {
                const float dd = duL[srow] + duL[10 + srow] + REG_C;
                if (diagA) vA += dd; else vB += dd;
            }
            *reinterpret_cast<float2*>(&SL[srow * 12 + sc1]) = make_float2(vA, vB);
        } else if (rLane) {
            rhs_loc = accA - (2.f * qwr + qh_a + ltL[lane] - ltL[10 + lane] +
                              ((lane == 0) ? nu : 0.f));
        }
        WFENCE();   // SL stores (lanes 10-59) ordered before SL reads (lanes 0-9)

        // ---- LU solve: rows on lanes 0-9; rhs LOCAL; pivot rcp prefetched ----
        float row[11], rBv;
        if (rLane) {
            const float4* s4 = reinterpret_cast<const float4*>(&SL[lane * 12]);
            const float4 q0 = s4[0], q1 = s4[1], q2 = s4[2];
            row[0] = q0.x; row[1] = q0.y; row[2] = q0.z; row[3] = q0.w;
            row[4] = q1.x; row[5] = q1.y; row[6] = q1.z; row[7] = q1.w;
            row[8] = q2.x; row[9] = q2.y;
        } else {
            #pragma unroll
            for (int c = 0; c < 10; ++c) row[c] = 0.f;
        }
        row[10] = rhs_loc;
        rBv = (lane == 0) ? 1.f : 0.f;

        float rd[10];            // rd[r] = frcp(own row[r]); filled as pivots finalize
        rd[0] = frcp(row[0]);
        #pragma unroll
        for (int kc = 0; kc < 9; ++kc) {
            float pk[11];
            #pragma unroll
            for (int c = kc + 1; c < 11; ++c) pk[c] = readlane_f(row[c], kc);
            const float pB = readlane_f(rBv, kc);
            const float rpiv = readlane_f(rd[kc], kc);   // prefetched reciprocal
            const float f = (lane > kc) ? row[kc] * rpiv : 0.f;
            #pragma unroll
            for (int c = kc + 1; c < 11; ++c) row[c] -= f * pk[c];
            rBv -= f * pB;
            rd[kc + 1] = frcp(row[kc + 1]);              // next pivot's rcp, off-chain
        }

        float dwAv[10], dwBv[10], ownA = 0.f, ownB = 0.f;
        #pragma unroll
        for (int r = 9; r >= 0; --r) {
            const float bA = readlane_f(row[10] * rd[r], r);
            const float bB = readlane_f(rBv * rd[r], r);
            dwAv[r] = bA; dwBv[r] = bB;
            if (jown == r) { ownA = bA; ownB = bB; }
            const float m_ = (lane < r) ? 1.f : 0.f;
            row[10] -= m_ * row[r] * bA;
            rBv     -= m_ * row[r] * bB;
        }

        const float rn = -(w1[0] - uu0);
        const float nu_d = (dwAv[0] - rn) * frcp(dwBv[0] + REG_C);
        float dw1[10];
        #pragma unroll
        for (int r = 0; r < 10; ++r) dw1[r] = dwAv[r] - nu_d * dwBv[r];
        const float dOwn = ownA - nu_d * ownB;

        f2 bd = mkf2(0.f, 0.f), qd = mkf2(0.f, 0.f);
        #pragma unroll
        for (int j = 0; j < 5; ++j) {
            const f2 dv = mkf2(dw1[2*j], dw1[2*j+1]);
            bd = fma2(mkf2(b[2*j], b[2*j+1]), dv, bd);
            qd = fma2(tB[j], dv, qd);            // Qh_row . dw1 (rhs lanes)
        }
        const float Bdw = bd.x + bd.y;
        const float qdw = qd.x + qd.y;

        // packed step computation
        const f2 Bdw2 = mkf2(Bdw, Bdw);
        const f2 dw2 = (rw2 + (d_BC * sgnP) * Bdw2) * rdD;   // (dw2a, dw2b)
        const f2 ds_BC = dw2 - rp_BC - sgnP * Bdw2;
        const f2 ds_DE = dw2 - rp_DE;
        const float ds_U = -sgnU * dOwn - rp_U;
        const f2 dl_BC = (mu2 - l_BC * (s_BC + ds_BC)) * rs_BC;
        const f2 dl_DE = (mu2 - l_DE * (s_DE + ds_DE)) * rs_DE;
        const float dl_U = (mu - l_U * (s_U + ds_U)) * rs_U;

        // ---- step ratios: q = max(-dv * (1/v)); negatives self-exclude ----
        f2 qf = max2(-ds_BC * rs_BC, -ds_DE * rs_DE);
        qf = max2(qf, -dl_BC * rl_BC);
        qf = max2(qf, -dl_DE * rl_DE);
        f2 pp1 = fma2(s_BC, dl_BC, l_BC * ds_BC);
        pp1 = fma2(s_DE, dl_DE, fma2(l_DE, ds_DE, pp1));
        f2 pp2 = fma2(ds_BC, dl_BC, ds_DE * dl_DE);

        float q  = a40 ? fmaxf(qf.x, qf.y) : 0.f;
        float p1 = a40 ? (pp1.x + pp1.y) : 0.f;
        float p2 = a40 ? (pp2.x + pp2.y) : 0.f;
        if (a20) {
            q = fmaxf(q, -ds_U * rs_U);
            q = fmaxf(q, -dl_U * rl_U);
            p1 += s_U * dl_U + l_U * ds_U;
            p2 += ds_U * dl_U;
        }
        RED3_DPP(0xB1);
        RED3_DPP(0x4E);
        RED3_DPP(0x141);
        RED3_DPP(0x140);
        p1 += DPPB(p1, 0x142, 0xA); p2 += DPPB(p2, 0x142, 0xA);
        q = fmaxf(q, DPPB(q, 0x142, 0xA));
        p1 += DPPB(p1, 0x143, 0xC); p2 += DPPB(p2, 0x143, 0xC);
        q = fmaxf(q, DPPB(q, 0x143, 0xC));
        const float qT  = readlane_f(q, 63);
        const float p1T = readlane_f(p1, 63);
        const float p2T = readlane_f(p2, 63);

        const float alpha = 0.99f * frcp(fmaxf(qT, 1.f));   // frcp(1)=1 exact
        mu = SIGMA_C * (p0T + alpha * (p1T + alpha * p2T)) * (1.f / 180.f);

        const f2 al2 = mkf2(alpha, alpha);
        s_BC = fma2(al2, ds_BC, s_BC); s_DE = fma2(al2, ds_DE, s_DE);
        l_BC = fma2(al2, dl_BC, l_BC); l_DE = fma2(al2, dl_DE, l_DE);
        s_U += alpha * ds_U; l_U += alpha * dl_U;
        w2 = fma2(al2, dw2, w2);
        #pragma unroll
        for (int r = 0; r < 10; ++r) w1[r] += alpha * dw1[r];
        w1own += alpha * dOwn;
        nu += alpha * nu_d;
        Bu  += alpha * Bdw;     // incremental b . w1
        qwr += alpha * qdw;     // incremental Qh_row . w1
        WFENCE();   // keep next iteration's LDS writes behind this one's reads
    }

    // ---------------- epilogue: cost ----------------
    if (lane == 0) {
        #pragma unroll
        for (int r = 0; r < 10; ++r) wL[r] = w1[r];
    }
    __syncthreads();
    float part = a40 ? (w2.x * w2.x + w2.y * w2.y) : 0.f;
    for (int idx = lane; idx < 100; idx += 64) {
        const int r = idx / 10, c = idx - r * 10;
        part += wL[r] * QhL[r * 12 + c] * wL[c];
    }
    if (lane < 10) part += pvL[lane] * wL[lane];
    for (int idx = lane; idx < 160; idx += 64) {
        const int i2 = idx >> 4, rc = idx & 15, rr2 = rc >> 2, cc2 = rc & 3;
        part += axL[i2 * 4 + rr2] * QL[rc] * axL[i2 * 4 + cc2];
    }
    if (lane == 0) {
        float ct = 0.f;
        #pragma unroll
        for (int r = 0; r < 4; ++r) {
            const float xr = (r == 0 ? xv0 : r == 1 ? xv1 : r == 2 ? xv2 : xv3);
            #pragma unroll
            for (int c = 0; c < 4; ++c) {
                const float xc = (c == 0 ? xv0 : c == 1 ? xv1 : c == 2 ? xv2 : xv3);
                ct += xr * QL[r * 4 + c] * xc;
            }
        }
        part += ct;
    }
    const float cost = wave_sum(part);
    if (lane == 0) {
        out[item] = cost;
        out[BATCH + item] = w1[0];
    }
}

extern "C" void kernel_launch(void* const* d_in, const int* in_sizes, int n_in,
                              void* d_out, int out_size, void* d_ws, size_t ws_size,
                              hipStream_t stream) {
    const float* x  = (const float*)d_in[0];
    const float* u0 = (const float*)d_in[1];
    const float* Qs = (const float*)d_in[2];
    const float* Rs = (const float*)d_in[3];
    const float* Ad = (const float*)d_in[4];
    const float* Bd = (const float*)d_in[5];
    float* outp = (float*)d_out;
    ipm_kernel<<<dim3(BATCH), dim3(64), 0, stream>>>(x, u0, Qs, Rs, Ad, Bd, outp);
}

// Round 12
// 91.939 us; speedup vs baseline: 1.0847x; 1.0230x over previous
//
#include <hip/hip_runtime.h>

#define BATCH 1024
#define ITERS 20
#define SIGMA_C 0.1f
#define REG_C 1e-8f

typedef float f2 __attribute__((ext_vector_type(2)));

__device__ __forceinline__ float frcp(float x) { return __builtin_amdgcn_rcpf(x); }
__device__ __forceinline__ float readlane_f(float v, int l) {
    return __int_as_float(__builtin_amdgcn_readlane(__float_as_int(v), l));
}
__device__ __forceinline__ f2 mkf2(float a, float b) { f2 r; r.x = a; r.y = b; return r; }
__device__ __forceinline__ f2 fma2(f2 a, f2 b, f2 c) { return a * b + c; }   // v_pk_fma_f32
__device__ __forceinline__ f2 max2(f2 a, f2 b) { return mkf2(fmaxf(a.x, b.x), fmaxf(a.y, b.y)); }
__device__ __forceinline__ f2 rcp2(f2 a) { return mkf2(frcp(a.x), frcp(a.y)); }

// Single-wave workgroup: LDS ops from one wave are processed in order by the
// LDS pipe, so write->read RAW needs no s_barrier / full lgkmcnt(0) drain.
#define WFENCE() do { __builtin_amdgcn_wave_barrier(); asm volatile("" ::: "memory"); } while (0)

// DPP helpers: ctrl/mask must be literals
#define DPPF(v, ctrl) \
    __int_as_float(__builtin_amdgcn_update_dpp(0, __float_as_int(v), ctrl, 0xf, 0xf, true))
#define DPPB(v, ctrl, rmask) \
    __int_as_float(__builtin_amdgcn_update_dpp(0, __float_as_int(v), ctrl, rmask, 0xf, false))

__device__ __forceinline__ float wave_sum(float v) {   // full-broadcast version (cold paths)
    v += DPPF(v, 0xB1);
    v += DPPF(v, 0x4E);
    v += DPPF(v, 0x141);
    v += DPPF(v, 0x140);
    v += __shfl_xor(v, 16);
    v += __shfl_xor(v, 32);
    return v;
}

// fused 3-stream intra-row reduction step (2 sums + 1 max)
#define RED3_DPP(ctrl) do { \
    p1 += DPPF(p1, ctrl); \
    p2 += DPPF(p2, ctrl); \
    q = fmaxf(q, DPPF(q, ctrl)); \
} while (0)

// One wave (64 lanes) per batch item. Lane k<40 owns constraint rows
// {B:20+k, C:60+k, D:100+k, E:140+k} packed as f2 pairs (B,C) and (D,E),
// plus e-vars w2=(w[10+k], w[50+k]). Lanes<20 own the u-box rows.
// w1[10] replicated. S-formation: lanes 10-59 own 2 adjacent S entries;
// lanes 0-9 own rhs row `lane` in-register.
// Solve: AUGMENTED 11x11 KKT [S, e0; e0^T, -REG] with single RHS — rows on
// lanes 0-10 (lane 10 = equality row), LU w/ readlane broadcasts.
__global__ __launch_bounds__(64, 1) void ipm_kernel(
    const float* __restrict__ x, const float* __restrict__ u0p,
    const float* __restrict__ Qs, const float* __restrict__ Rs,
    const float* __restrict__ Ad, const float* __restrict__ Bd,
    float* __restrict__ out)
{
    const int item = blockIdx.x;
    const int lane = threadIdx.x;

    __shared__ __align__(16) float BLc[10 * 40];  // B column-major: BLc[j][k]=B[k][j]
    __shared__ __align__(16) float QBc[10 * 40];  // (Q_diag B) column-major
    __shared__ __align__(16) float yL4[40];
    __shared__ __align__(16) float QhL[10 * 12];
    __shared__ __align__(16) float SL[10 * 12];   // cols 0-9 = S
    __shared__ __align__(16) float cg[80];        // [0,40)=coeff, [40,80)=gvc
    __shared__ float duL[20], ltL[20];
    __shared__ float axL[40];
    __shared__ float pvL[10], wL[10];
    __shared__ float QL[16];
    __shared__ float TL[40];    // T[i][r] = (A^i B)[r]
    __shared__ float AhL[160];  // A_hat [40][4]

    // ---------------- prologue ----------------
    const int r2 = (lane >> 2) & 3, c2 = lane & 3;
    const int r4 = lane & 3;

    if (lane < 16) {
        float acc = 0.f;
        #pragma unroll
        for (int k = 0; k < 4; ++k) acc += Qs[r2 * 4 + k] * Qs[c2 * 4 + k];
        QL[lane] = acc;
    }

    // A powers -> A_hat (shfl chain)
    float acol[4];
    #pragma unroll
    for (int k = 0; k < 4; ++k) acol[k] = Ad[k * 4 + c2];
    float cur = Ad[r2 * 4 + c2];
    if (lane < 16) AhL[r2 * 4 + c2] = cur;
    #pragma unroll
    for (int i = 1; i < 10; ++i) {
        float nx = 0.f;
        #pragma unroll
        for (int k = 0; k < 4; ++k) nx += __shfl(cur, r2 * 4 + k) * acol[k];
        cur = nx;
        if (lane < 16) AhL[(4 * i + r2) * 4 + c2] = cur;
    }

    // T chain
    float arow[4];
    #pragma unroll
    for (int k = 0; k < 4; ++k) arow[k] = Ad[r4 * 4 + k];
    float tc = Bd[r4];
    if (lane < 4) TL[r4] = tc;
    #pragma unroll
    for (int i = 1; i < 10; ++i) {
        float nt = 0.f;
        #pragma unroll
        for (int k = 0; k < 4; ++k) nt += arow[k] * __shfl(tc, k);
        tc = nt;
        if (lane < 4) TL[i * 4 + r4] = nt;
    }
    __syncthreads();

    // per-lane B_hat row
    const int kk40 = (lane < 40) ? lane : 39;
    const int ib = lane >> 2;
    float b[10];
    #pragma unroll
    for (int j = 0; j < 10; ++j) {
        int dd = ib - j;
        int dc = dd < 0 ? 0 : (dd > 9 ? 9 : dd);
        float v = TL[dc * 4 + r4];
        b[j] = (dd >= 0 && lane < 40) ? v : 0.f;
    }

    const float xv0 = x[item * 4 + 0], xv1 = x[item * 4 + 1];
    const float xv2 = x[item * 4 + 2], xv3 = x[item * 4 + 3];
    const float ax = AhL[kk40 * 4 + 0] * xv0 + AhL[kk40 * 4 + 1] * xv1 +
                     AhL[kk40 * 4 + 2] * xv2 + AhL[kk40 * 4 + 3] * xv3;
    if (lane < 40) axL[lane] = ax;

    const int gbase = lane & ~3;
    float yv = 0.f;
    #pragma unroll
    for (int rp_ = 0; rp_ < 4; ++rp_) yv += QL[r4 * 4 + rp_] * __shfl(ax, gbase + rp_);
    if (lane < 40) yL4[lane] = yv;
    #pragma unroll
    for (int cc = 0; cc < 10; ++cc) {
        float acc = 0.f;
        #pragma unroll
        for (int rp_ = 0; rp_ < 4; ++rp_) acc += QL[r4 * 4 + rp_] * __shfl(b[cc], gbase + rp_);
        if (lane < 40) QBc[cc * 40 + lane] = acc;
    }
    if (lane < 40) {
        #pragma unroll
        for (int j = 0; j < 10; ++j) BLc[j * 40 + lane] = b[j];
    }
    __syncthreads();

    // pv (lanes 0-9)
    if (lane < 10) {
        const float4* br = reinterpret_cast<const float4*>(&BLc[lane * 40]);
        const float4* yy = reinterpret_cast<const float4*>(yL4);
        float acc = 0.f;
        #pragma unroll
        for (int i = 0; i < 10; ++i) {
            const float4 a_ = br[i], b_ = yy[i];
            acc += a_.x * b_.x + a_.y * b_.y + a_.z * b_.z + a_.w * b_.w;
        }
        pvL[lane] = 2.f * acc;
    }
    // Qh (100 tasks)
    const float R2v = Rs[0] * Rs[0];
    #pragma unroll
    for (int p = 0; p < 2; ++p) {
        const int t = lane + 64 * p;
        if (t < 100) {
            const int aa = t / 10, bb = t - aa * 10;
            const float4* ba = reinterpret_cast<const float4*>(&BLc[aa * 40]);
            const float4* qb = reinterpret_cast<const float4*>(&QBc[bb * 40]);
            float acc = (aa == bb) ? R2v : 0.f;
            #pragma unroll
            for (int i = 0; i < 10; ++i) {
                const float4 a_ = ba[i], b_ = qb[i];
                acc += a_.x * b_.x + a_.y * b_.y + a_.z * b_.z + a_.w * b_.w;
            }
            QhL[aa * 12 + bb] = acc;
        }
    }
    __syncthreads();

    // ---------------- per-lane register task caches (packed f2) ----------------
    const bool rLane = (lane < 10);                  // rhs producers == solve rows
    const bool sLane = (lane >= 10 && lane < 60);    // S-entry pairs
    const int t1 = sLane ? 2 * (lane - 10) : 0;
    const int srow = t1 / 10, sc1 = t1 - srow * 10, sc2 = sc1 + 1;
    f2 tA[20], tB[20];
    #pragma unroll
    for (int i = 0; i < 20; ++i) { tA[i] = mkf2(0.f, 0.f); tB[i] = mkf2(0.f, 0.f); }
    float qh_a = 0.f, qh_b = 0.f;
    bool diagA = false, diagB = false;
    if (sLane) {
        const float4* br = reinterpret_cast<const float4*>(&BLc[srow * 40]);
        const float4* b1 = reinterpret_cast<const float4*>(&BLc[sc1 * 40]);
        const float4* b2 = reinterpret_cast<const float4*>(&BLc[sc2 * 40]);
        #pragma unroll
        for (int i = 0; i < 10; ++i) {
            const float4 r_ = br[i], u_ = b1[i], v_ = b2[i];
            tA[2*i]   = mkf2(r_.x * u_.x, r_.y * u_.y);
            tA[2*i+1] = mkf2(r_.z * u_.z, r_.w * u_.w);
            tB[2*i]   = mkf2(r_.x * v_.x, r_.y * v_.y);
            tB[2*i+1] = mkf2(r_.z * v_.z, r_.w * v_.w);
        }
        qh_a = 2.f * QhL[srow * 12 + sc1];
        qh_b = 2.f * QhL[srow * 12 + sc2];
        diagA = (srow == sc1); diagB = (srow == sc2);
    } else if (rLane) {
        const float4* br = reinterpret_cast<const float4*>(&BLc[lane * 40]);
        #pragma unroll
        for (int i = 0; i < 10; ++i) {
            const float4 r_ = br[i];
            tA[2*i]   = mkf2(r_.x, r_.y);
            tA[2*i+1] = mkf2(r_.z, r_.w);
        }
        #pragma unroll
        for (int c = 0; c < 5; ++c)
            tB[c] = mkf2(QhL[lane * 12 + 2*c], QhL[lane * 12 + 2*c + 1]);
        qh_a = pvL[lane];
    }
    __syncthreads();

    // ---------------- state init (f2-packed: x=B, y=C / x=D, y=E) ----------------
    const f2 hBC = mkf2(4.f - ax, 4.f + ax);
    const f2 sgnP = mkf2(1.f, -1.f);
    f2 s_BC = mkf2(fmaxf(hBC.x, 1.f), fmaxf(hBC.y, 1.f));
    f2 s_DE = mkf2(1.f, 1.f);
    f2 l_BC = mkf2(1.f, 1.f), l_DE = mkf2(1.f, 1.f);
    float s_U = 1.f, l_U = 1.f;
    f2 w2 = mkf2(0.f, 0.f);
    float w1[10];
    #pragma unroll
    for (int r = 0; r < 10; ++r) w1[r] = 0.f;
    float w1own = 0.f, nu = 0.f;
    float Bu = 0.f;      // running b . w1
    float qwr = 0.f;     // running Qh_row . w1 (rhs lanes)
    const float uu0 = u0p[item];
    const bool a40 = lane < 40, a20 = lane < 20;
    const int jown = (lane < 10) ? lane : lane - 10;
    const float sgnU = (lane < 10) ? 1.f : -1.f;

    // initial mu = SIGMA * sum(s*l)/180 (l == 1)
    float mu;
    {
        float part = a40 ? (s_BC.x + s_BC.y + s_DE.x + s_DE.y) : 0.f;
        if (a20) part += s_U;
        mu = SIGMA_C * wave_sum(part) * (1.f / 180.f);
    }

    // ---------------- IPM iterations ----------------
    for (int it = 0; it < ITERS; ++it) {
        const f2 rs_BC = rcp2(s_BC), rs_DE = rcp2(s_DE);
        const f2 rl_BC = rcp2(l_BC), rl_DE = rcp2(l_DE);
        const float rs_U = frcp(s_U), rl_U = frcp(l_U);
        const f2 d_BC = l_BC * rs_BC, d_DE = l_DE * rs_DE;
        const float d_U = l_U * rs_U;

        // residuals (packed)
        const f2 gw = sgnP * Bu - w2;            // (Bu - w2a, -Bu - w2b)
        const f2 rp_BC = gw + s_BC - hBC;
        const f2 rp_DE = s_DE - w2;
        const float rp_U = sgnU * w1own + s_U - 0.5f;

        const f2 mu2 = mkf2(mu, mu);
        const f2 tm_BC = (mu2 - l_BC * (s_BC - rp_BC)) * rs_BC;
        const f2 tm_DE = (mu2 - l_DE * (s_DE - rp_DE)) * rs_DE;
        const float tm_U = (mu - l_U * (s_U - rp_U)) * rs_U;
        const f2 lt_BC = l_BC + tm_BC, lt_DE = l_DE + tm_DE;

        const f2 D22 = d_BC + d_DE + mkf2(2.f + REG_C, 2.f + REG_C);  // (D22a, D22b)
        const f2 rdD = rcp2(D22);
        const f2 rw2 = lt_BC + lt_DE - 2.f * w2;                      // (rw2a, rw2b)
        const float coeff = (d_BC.x + d_BC.y) - d_BC.x * d_BC.x * rdD.x
                                              - d_BC.y * d_BC.y * rdD.y;
        const float gvc = (d_BC.x * rw2.x * rdD.x - d_BC.y * rw2.y * rdD.y)
                          - (lt_BC.x - lt_BC.y);

        if (a40) { cg[lane] = coeff; cg[40 + lane] = gvc; }
        if (a20) { duL[lane] = d_U; ltL[lane] = l_U + tm_U; }
        WFENCE();   // single wave: in-order DS pipe makes RAW safe without barrier

        // ---- cf loads issued immediately (pipeline behind the writes) ----
        float4 cf4[10];
        {
            const float4* cp = reinterpret_cast<const float4*>(cg + (rLane ? 40 : 0));
            #pragma unroll
            for (int i = 0; i < 10; ++i) cf4[i] = cp[i];
        }

        // ---- p0 = sum(s*l) reduction in the load shadow (DPP bcast tail) ----
        f2 pp0 = fma2(s_BC, l_BC, s_DE * l_DE);
        float p0 = a40 ? (pp0.x + pp0.y) : 0.f;
        if (a20) p0 += s_U * l_U;
        p0 += DPPF(p0, 0xB1);
        p0 += DPPF(p0, 0x4E);
        p0 += DPPF(p0, 0x141);
        p0 += DPPF(p0, 0x140);
        p0 += DPPB(p0, 0x142, 0xA);   // row_bcast15 into rows 1,3
        p0 += DPPB(p0, 0x143, 0xC);   // row_bcast31 into rows 2,3
        const float p0T = readlane_f(p0, 63);

        // ---- unified dot loops (identical shape for S-lanes and rhs-lanes) ----
        f2 aA0 = mkf2(0.f, 0.f), aA1 = mkf2(0.f, 0.f);
        f2 aB0 = mkf2(0.f, 0.f), aB1 = mkf2(0.f, 0.f);
        #pragma unroll
        for (int i = 0; i < 10; ++i) {
            const f2 cl = mkf2(cf4[i].x, cf4[i].y);
            const f2 ch = mkf2(cf4[i].z, cf4[i].w);
            aA0 = fma2(tA[2*i], cl, aA0); aA1 = fma2(tA[2*i+1], ch, aA1);
            aB0 = fma2(tB[2*i], cl, aB0); aB1 = fma2(tB[2*i+1], ch, aB1);
        }
        const float accA = (aA0.x + aA0.y) + (aA1.x + aA1.y);
        const float accB = (aB0.x + aB0.y) + (aB1.x + aB1.y);

        float rhs_loc = 0.f;
        if (sLane) {
            float vA = accA + qh_a, vB = accB + qh_b;
            if (diagA || diagB) {
                const float dd = duL[srow] + duL[10 + srow] + REG_C;
                if (diagA) vA += dd; else vB += dd;
            }
            *reinterpret_cast<float2*>(&SL[srow * 12 + sc1]) = make_float2(vA, vB);
        } else if (rLane) {
            rhs_loc = accA - (2.f * qwr + qh_a + ltL[lane] - ltL[10 + lane] +
                              ((lane == 0) ? nu : 0.f));
        }
        WFENCE();   // SL stores (lanes 10-59) ordered before SL reads (lanes 0-9)

        // ---- augmented 11x11 LU: rows on lanes 0-10, single RHS ----
        // cols 0-9 = S, col 10 = e0 column, col 11 = rhs
        float row[12];
        if (rLane) {
            const float4* s4 = reinterpret_cast<const float4*>(&SL[lane * 12]);
            const float4 q0 = s4[0], q1 = s4[1], q2 = s4[2];
            row[0] = q0.x; row[1] = q0.y; row[2] = q0.z; row[3] = q0.w;
            row[4] = q1.x; row[5] = q1.y; row[6] = q1.z; row[7] = q1.w;
            row[8] = q2.x; row[9] = q2.y;
            row[10] = (lane == 0) ? 1.f : 0.f;
            row[11] = rhs_loc;
        } else if (lane == 10) {
            row[0] = 1.f;
            #pragma unroll
            for (int c = 1; c < 10; ++c) row[c] = 0.f;
            row[10] = -REG_C;
            row[11] = uu0 - w1[0];                 // rn
        } else {
            #pragma unroll
            for (int c = 0; c < 12; ++c) row[c] = 0.f;
        }

        float rd[11];            // rd[r] = frcp(own row[r]); filled as pivots finalize
        rd[0] = frcp(row[0]);
        #pragma unroll
        for (int kc = 0; kc < 10; ++kc) {
            float pk[12];
            #pragma unroll
            for (int c = kc + 1; c < 12; ++c) pk[c] = readlane_f(row[c], kc);
            const float rpiv = readlane_f(rd[kc], kc);   // prefetched reciprocal
            const float f = (lane > kc) ? row[kc] * rpiv : 0.f;
            #pragma unroll
            for (int c = kc + 1; c < 12; ++c) row[c] -= f * pk[c];
            rd[kc + 1] = frcp(row[kc + 1]);              // next pivot's rcp, off-chain
        }

        // back-substitution: z[10] = nu_d, z[0..9] = dw1
        float dw1[10], nu_d = 0.f, dOwn = 0.f;
        #pragma unroll
        for (int r = 10; r >= 0; --r) {
            const float zr = readlane_f(row[11] * rd[r], r);
            if (r == 10) nu_d = zr;
            else { dw1[r] = zr; if (jown == r) dOwn = zr; }
            const float m_ = (lane < r) ? 1.f : 0.f;
            row[11] -= m_ * row[r] * zr;
        }

        f2 bd = mkf2(0.f, 0.f), qd = mkf2(0.f, 0.f);
        #pragma unroll
        for (int j = 0; j < 5; ++j) {
            const f2 dv = mkf2(dw1[2*j], dw1[2*j+1]);
            bd = fma2(mkf2(b[2*j], b[2*j+1]), dv, bd);
            qd = fma2(tB[j], dv, qd);            // Qh_row . dw1 (rhs lanes)
        }
        const float Bdw = bd.x + bd.y;
        const float qdw = qd.x + qd.y;

        // packed step computation
        const f2 Bdw2 = mkf2(Bdw, Bdw);
        const f2 dw2 = (rw2 + (d_BC * sgnP) * Bdw2) * rdD;   // (dw2a, dw2b)
        const f2 ds_BC = dw2 - rp_BC - sgnP * Bdw2;
        const f2 ds_DE = dw2 - rp_DE;
        const float ds_U = -sgnU * dOwn - rp_U;
        const f2 dl_BC = (mu2 - l_BC * (s_BC + ds_BC)) * rs_BC;
        const f2 dl_DE = (mu2 - l_DE * (s_DE + ds_DE)) * rs_DE;
        const float dl_U = (mu - l_U * (s_U + ds_U)) * rs_U;

        // ---- step ratios: q = max(-dv * (1/v)); negatives self-exclude ----
        f2 qf = max2(-ds_BC * rs_BC, -ds_DE * rs_DE);
        qf = max2(qf, -dl_BC * rl_BC);
        qf = max2(qf, -dl_DE * rl_DE);
        f2 pp1 = fma2(s_BC, dl_BC, l_BC * ds_BC);
        pp1 = fma2(s_DE, dl_DE, fma2(l_DE, ds_DE, pp1));
        f2 pp2 = fma2(ds_BC, dl_BC, ds_DE * dl_DE);

        float q  = a40 ? fmaxf(qf.x, qf.y) : 0.f;
        float p1 = a40 ? (pp1.x + pp1.y) : 0.f;
        float p2 = a40 ? (pp2.x + pp2.y) : 0.f;
        if (a20) {
            q = fmaxf(q, -ds_U * rs_U);
            q = fmaxf(q, -dl_U * rl_U);
            p1 += s_U * dl_U + l_U * ds_U;
            p2 += ds_U * dl_U;
        }
        RED3_DPP(0xB1);
        RED3_DPP(0x4E);
        RED3_DPP(0x141);
        RED3_DPP(0x140);
        p1 += DPPB(p1, 0x142, 0xA); p2 += DPPB(p2, 0x142, 0xA);
        q = fmaxf(q, DPPB(q, 0x142, 0xA));
        p1 += DPPB(p1, 0x143, 0xC); p2 += DPPB(p2, 0x143, 0xC);
        q = fmaxf(q, DPPB(q, 0x143, 0xC));
        const float qT  = readlane_f(q, 63);
        const float p1T = readlane_f(p1, 63);
        const float p2T = readlane_f(p2, 63);

        const float alpha = 0.99f * frcp(fmaxf(qT, 1.f));   // frcp(1)=1 exact
        mu = SIGMA_C * (p0T + alpha * (p1T + alpha * p2T)) * (1.f / 180.f);

        const f2 al2 = mkf2(alpha, alpha);
        s_BC = fma2(al2, ds_BC, s_BC); s_DE = fma2(al2, ds_DE, s_DE);
        l_BC = fma2(al2, dl_BC, l_BC); l_DE = fma2(al2, dl_DE, l_DE);
        s_U += alpha * ds_U; l_U += alpha * dl_U;
        w2 = fma2(al2, dw2, w2);
        #pragma unroll
        for (int r = 0; r < 10; ++r) w1[r] += alpha * dw1[r];
        w1own += alpha * dOwn;
        nu += alpha * nu_d;
        Bu  += alpha * Bdw;     // incremental b . w1
        qwr += alpha * qdw;     // incremental Qh_row . w1
        WFENCE();   // keep next iteration's LDS writes behind this one's reads
    }

    // ---------------- epilogue: cost ----------------
    if (lane == 0) {
        #pragma unroll
        for (int r = 0; r < 10; ++r) wL[r] = w1[r];
    }
    __syncthreads();
    float part = a40 ? (w2.x * w2.x + w2.y * w2.y) : 0.f;
    for (int idx = lane; idx < 100; idx += 64) {
        const int r = idx / 10, c = idx - r * 10;
        part += wL[r] * QhL[r * 12 + c] * wL[c];
    }
    if (lane < 10) part += pvL[lane] * wL[lane];
    for (int idx = lane; idx < 160; idx += 64) {
        const int i2 = idx >> 4, rc = idx & 15, rr2 = rc >> 2, cc2 = rc & 3;
        part += axL[i2 * 4 + rr2] * QL[rc] * axL[i2 * 4 + cc2];
    }
    if (lane == 0) {
        float ct = 0.f;
        #pragma unroll
        for (int r = 0; r < 4; ++r) {
            const float xr = (r == 0 ? xv0 : r == 1 ? xv1 : r == 2 ? xv2 : xv3);
            #pragma unroll
            for (int c = 0; c < 4; ++c) {
                const float xc = (c == 0 ? xv0 : c == 1 ? xv1 : c == 2 ? xv2 : xv3);
                ct += xr * QL[r * 4 + c] * xc;
            }
        }
        part += ct;
    }
    const float cost = wave_sum(part);
    if (lane == 0) {
        out[item] = cost;
        out[BATCH + item] = w1[0];
    }
}

extern "C" void kernel_launch(void* const* d_in, const int* in_sizes, int n_in,
                              void* d_out, int out_size, void* d_ws, size_t ws_size,
                              hipStream_t stream) {
    const float* x  = (const float*)d_in[0];
    const float* u0 = (const float*)d_in[1];
    const float* Qs = (const float*)d_in[2];
    const float* Rs = (const float*)d_in[3];
    const float* Ad = (const float*)d_in[4];
    const float* Bd = (const float*)d_in[5];
    float* outp = (float*)d_out;
    ipm_kernel<<<dim3(BATCH), dim3(64), 0, stream>>>(x, u0, Qs, Rs, Ad, Bd, outp);
}